// Round 1
// baseline (130.620 us; speedup 1.0000x reference)
//
#include <hip/hip_runtime.h>
#include <stdint.h>

#define N_PTS 4096
#define BATCH 4
#define C_IN  128
#define C_OUT 256
#define KDIM  1024   // 8 active slots * 128 channels (octant-7 slot is provably always zero)

typedef __attribute__((ext_vector_type(8))) __bf16 bf16x8;
typedef __attribute__((ext_vector_type(4))) float  f32x4;

__device__ inline void gload_lds16(const void* g, void* l) {
    __builtin_amdgcn_global_load_lds(
        (__attribute__((address_space(1))) void*)(void*)(uintptr_t)g,
        (__attribute__((address_space(3))) void*)l, 16, 0, 0);
}

__device__ inline unsigned short f2bf(float v) {
    uint32_t u = __builtin_bit_cast(uint32_t, v);
    return (unsigned short)((u + 0x7fffu + ((u >> 16) & 1u)) >> 16);   // RTNE
}

// ---------------- kernel 1: ball query + per-octant first neighbor ----------------
// One wave per point. Scans all 4096 candidates in ascending index order,
// counts within-radius matches (cap 31 = S-1), records first match per octant 0..6.
// Lane l (l<7) holds first[l]. Output idx8[g][0]=center n, [1+o]=first or 4096.
__global__ __launch_bounds__(256) void bq_kernel(const float* __restrict__ pcs,
                                                 int* __restrict__ idx8) {
    __shared__ float4 pts[N_PTS];   // x,y,z,sq  (64 KB)
    const int tid = threadIdx.x;
    const int b = blockIdx.x >> 10;           // 1024 blocks per batch
    const float* pb = pcs + (size_t)b * 3 * N_PTS;
    for (int i = tid; i < N_PTS; i += 256) {
        float x = pb[i], y = pb[N_PTS + i], z = pb[2 * N_PTS + i];
        // match reference: sq = ((x*x + y*y) + z*z), no FMA contraction
        float sq = __fadd_rn(__fadd_rn(__fmul_rn(x, x), __fmul_rn(y, y)), __fmul_rn(z, z));
        pts[i] = make_float4(x, y, z, sq);
    }
    __syncthreads();
    const int wid = tid >> 6, lane = tid & 63;
    const int n = ((blockIdx.x & 1023) << 2) | wid;
    const int g = (b << 12) | n;
    const float4 c = pts[n];
    const float r2 = (float)(0.12 * 0.12);
    int first_val = -1;
    int taken = 0;
    for (int ch = 0; ch < 64; ++ch) {
        const int j = (ch << 6) | lane;
        const float4 p = pts[j];
        // match reference: d2 = (sq_n + sq_m) - 2*dot, dot = ((xx+yy)+zz)
        float dot = __fadd_rn(__fadd_rn(__fmul_rn(c.x, p.x), __fmul_rn(c.y, p.y)),
                              __fmul_rn(c.z, p.z));
        float d2 = __fsub_rn(__fadd_rn(c.w, p.w), __fmul_rn(2.0f, dot));
        bool ok = (d2 <= r2) && (j != n);
        unsigned long long m = __ballot(ok);
        if (m) {
            unsigned long long bx = __ballot(p.x >= c.x);
            unsigned long long by = __ballot(p.y >= c.y);
            unsigned long long bz = __ballot(p.z >= c.z);
            while (m) {
                int t = __builtin_ctzll(m);
                m &= m - 1;
                int oct = (int)((bx >> t) & 1) * 4 + (int)((by >> t) & 1) * 2 + (int)((bz >> t) & 1);
                bool mine = (oct < 7) && (lane == oct) && (first_val < 0);
                if (mine) first_val = (ch << 6) | t;
                ++taken;
                if (taken >= 31) break;
            }
            unsigned long long fm = __ballot(first_val >= 0) & 0x7full;
            if (taken >= 31 || fm == 0x7full) break;
        }
    }
    if (lane == 0) idx8[(size_t)g * 8] = n;
    if (lane < 7) idx8[(size_t)g * 8 + 1 + lane] = (first_val < 0) ? N_PTS : first_val;
}

// ---------------- kernel 2: transpose x [B,C,N] fp32 -> xbf [B][N+1][C] bf16 ----------
__global__ __launch_bounds__(256) void xpose_kernel(const float* __restrict__ x,
                                                    unsigned short* __restrict__ xbf) {
    __shared__ __attribute__((aligned(16))) unsigned short tile[64 * 132];
    const int tid = threadIdx.x;
    const int b = blockIdx.x / 65;
    const int j0 = (blockIdx.x % 65) * 64;
    if (j0 < N_PTS) {
        for (int c0 = 0; c0 < C_IN; c0 += 4) {
            int cc = c0 + (tid >> 6);
            int jj = tid & 63;
            float v = x[((size_t)b * C_IN + cc) * N_PTS + j0 + jj];
            tile[jj * 132 + cc] = f2bf(v);
        }
        __syncthreads();
        for (int i = 0; i < 8; ++i) {
            int idx = i * 256 + tid;          // 0..2047 -> 64 rows x 32 quads
            int row = idx >> 5, cq = idx & 31;
            uint2 v = *(const uint2*)&tile[row * 132 + cq * 4];
            *(uint2*)&xbf[((size_t)b * (N_PTS + 1) + j0 + row) * C_IN + cq * 4] = v;
        }
    } else {
        // zeros row j = 4096 (empty-octant gather target)
        for (int i = tid; i < C_IN; i += 256)
            xbf[((size_t)b * (N_PTS + 1) + N_PTS) * C_IN + i] = 0;
    }
}

// ---------------- kernel 3: weight [256,128,1,9] fp32 -> wt [o][kappa=slot*128+c] bf16 --
__global__ __launch_bounds__(256) void wprep_kernel(const float* __restrict__ w,
                                                    unsigned short* __restrict__ wt) {
    int gidx = blockIdx.x * 256 + threadIdx.x;    // 0..262143
    int o = gidx >> 10, k = gidx & 1023;
    int slot = k >> 7, cch = k & 127;             // slot 0=center(w k=0), slot s=octant s-1 (w k=s)
    wt[gidx] = f2bf(w[(size_t)o * 1152 + cch * 9 + slot]);
}

// ---------------- kernel 4: gathered GEMM, bf16 MFMA 16x16x32 ----------------------
// D[o][n] = sum_kappa W[o][kappa] * P[n][kappa];  M-tile 64 points, N-tile 64 outs,
// BK=64, 4 waves each computing 32x32. LDS XOR-swizzle (slot ^= row&7) applied via
// pre-swizzled per-lane GLOBAL source (global_load_lds writes linearly) + swizzled read.
__global__ __launch_bounds__(256) void pconv_gemm(const unsigned short* __restrict__ xbf,
                                                  const unsigned short* __restrict__ wt,
                                                  const int* __restrict__ idx8,
                                                  const float* __restrict__ bias,
                                                  float* __restrict__ out) {
    __shared__ __attribute__((aligned(16))) unsigned short Plds[64 * 64];
    __shared__ __attribute__((aligned(16))) unsigned short Wlds[64 * 64];
    const int tid = threadIdx.x;
    const int tm = blockIdx.x >> 2, tn = blockIdx.x & 3;
    const int g0 = tm * 64;                  // global point-row base
    const int b  = g0 >> 12;
    const int nb = g0 & 4095;
    const int o0 = tn * 64;
    const int wid = tid >> 6, lane = tid & 63;
    const int wo = wid >> 1, wn = wid & 1;

    f32x4 acc[2][2] = {};

    for (int it = 0; it < 16; ++it) {
        const int k0 = it << 6;
        const int slot_id = k0 >> 7;         // which of the 8 gather slots
        const int cb = k0 & 127;             // channel base within slot
#pragma unroll
        for (int i = 0; i < 2; ++i) {
            const int Lb = i * 256 + wid * 64;          // wave-uniform 16B-slot base
            const int row = (Lb + lane) >> 3;           // tile row this lane feeds
            const int slog = (lane & 7) ^ (row & 7);    // pre-swizzled source slot
            // P: gathered point features
            int j = idx8[(size_t)(g0 + row) * 8 + slot_id];
            const unsigned short* psrc =
                xbf + ((size_t)b * (N_PTS + 1) + j) * C_IN + cb + slog * 8;
            gload_lds16(psrc, &Plds[Lb * 8]);
            // W: weight rows
            const unsigned short* wsrc =
                wt + (size_t)(o0 + row) * KDIM + k0 + slog * 8;
            gload_lds16(wsrc, &Wlds[Lb * 8]);
        }
        __syncthreads();
#pragma unroll
        for (int ks = 0; ks < 2; ++ks) {
            bf16x8 wf[2], pf[2];
#pragma unroll
            for (int f = 0; f < 2; ++f) {
                int orow = wo * 32 + f * 16 + (lane & 15);
                int slw = (ks * 4 + (lane >> 4)) ^ (orow & 7);
                wf[f] = *(const bf16x8*)&Wlds[orow * 64 + slw * 8];
                int nrow = wn * 32 + f * 16 + (lane & 15);
                int slp = (ks * 4 + (lane >> 4)) ^ (nrow & 7);
                pf[f] = *(const bf16x8*)&Plds[nrow * 64 + slp * 8];
            }
#pragma unroll
            for (int of = 0; of < 2; ++of)
#pragma unroll
                for (int nf = 0; nf < 2; ++nf)
                    acc[of][nf] = __builtin_amdgcn_mfma_f32_16x16x32_bf16(
                        wf[of], pf[nf], acc[of][nf], 0, 0, 0);
        }
        __syncthreads();
    }

#pragma unroll
    for (int of = 0; of < 2; ++of) {
        int o = o0 + wo * 32 + of * 16 + (lane >> 4) * 4;
#pragma unroll
        for (int nf = 0; nf < 2; ++nf) {
            int n = nb + wn * 32 + nf * 16 + (lane & 15);
#pragma unroll
            for (int r = 0; r < 4; ++r) {
                out[((size_t)b * C_OUT + o + r) * N_PTS + n] = acc[of][nf][r] + bias[o + r];
            }
        }
    }
}

extern "C" void kernel_launch(void* const* d_in, const int* in_sizes, int n_in,
                              void* d_out, int out_size, void* d_ws, size_t ws_size,
                              hipStream_t stream) {
    const float* x    = (const float*)d_in[0];
    const float* pcs  = (const float*)d_in[1];
    const float* w    = (const float*)d_in[2];
    const float* bias = (const float*)d_in[3];

    // ws layout: xbf [4*4097*128] bf16 | wt [256*1024] bf16 | idx8 [16384*8] int
    unsigned short* xbf = (unsigned short*)d_ws;
    unsigned short* wt  = xbf + (size_t)BATCH * (N_PTS + 1) * C_IN;
    int* idx8 = (int*)(wt + (size_t)C_OUT * KDIM);
    float* out = (float*)d_out;

    hipLaunchKernelGGL(bq_kernel,    dim3(4096),      dim3(256), 0, stream, pcs, idx8);
    hipLaunchKernelGGL(xpose_kernel, dim3(BATCH * 65), dim3(256), 0, stream, x, xbf);
    hipLaunchKernelGGL(wprep_kernel, dim3(1024),      dim3(256), 0, stream, w, wt);
    hipLaunchKernelGGL(pconv_gemm,   dim3(1024),      dim3(256), 0, stream,
                       xbf, wt, idx8, bias, out);
}

// Round 2
// 93.282 us; speedup vs baseline: 1.4003x; 1.4003x over previous
//
#include <hip/hip_runtime.h>
#include <stdint.h>

#define N_PTS 4096
#define BATCH 4
#define C_IN  128
#define C_OUT 256
#define KDIM  1024   // 8 active slots * 128 channels (octant-7 slot is provably always zero)

typedef __attribute__((ext_vector_type(8))) __bf16 bf16x8;
typedef __attribute__((ext_vector_type(4))) float  f32x4;

__device__ inline void gload_lds16(const void* g, void* l) {
    __builtin_amdgcn_global_load_lds(
        (__attribute__((address_space(1))) void*)(void*)(uintptr_t)g,
        (__attribute__((address_space(3))) void*)l, 16, 0, 0);
}

__device__ inline unsigned short f2bf(float v) {
    uint32_t u = __builtin_bit_cast(uint32_t, v);
    return (unsigned short)((u + 0x7fffu + ((u >> 16) & 1u)) >> 16);   // RTNE
}

// ---------------- kernel 0: prep — weight transpose + packed pts4 ----------------
// blocks 0..1023: wt[o][kappa] bf16; blocks 1024..1087: pts4[b][n] = (x,y,z,sq)
__global__ __launch_bounds__(256) void prep_kernel(const float* __restrict__ w,
                                                   unsigned short* __restrict__ wt,
                                                   const float* __restrict__ pcs,
                                                   float4* __restrict__ pts4) {
    const int bid = blockIdx.x;
    if (bid < 1024) {
        int gidx = bid * 256 + threadIdx.x;           // 0..262143
        int o = gidx >> 10, k = gidx & 1023;
        int slot = k >> 7, cch = k & 127;             // slot 0=center, slot s=octant s-1
        wt[gidx] = f2bf(w[(size_t)o * 1152 + cch * 9 + slot]);
    } else {
        int i = (bid - 1024) * 256 + threadIdx.x;     // 0..16383
        int b = i >> 12, n = i & 4095;
        const float* pb = pcs + (size_t)b * 3 * N_PTS;
        float x = pb[n], y = pb[N_PTS + n], z = pb[2 * N_PTS + n];
        // match reference: sq = ((x*x + y*y) + z*z), no FMA contraction
        float sq = __fadd_rn(__fadd_rn(__fmul_rn(x, x), __fmul_rn(y, y)), __fmul_rn(z, z));
        pts4[i] = make_float4(x, y, z, sq);
    }
}

// ---------------- kernel 1: ball query + per-octant first neighbor ----------------
// 4 centers per wave (ILP to hide L2 latency), no LDS. Lane 8c+o holds first[o]
// of center c. Candidates scanned 64 at a time in ascending index order; matches
// consumed serially per chunk (preserves the taken<31 cap semantics exactly).
__global__ __launch_bounds__(256) void bq_kernel(const float4* __restrict__ pts4,
                                                 int* __restrict__ idx8) {
    const int tid = threadIdx.x;
    const int wid = tid >> 6, lane = tid & 63;
    const int b = blockIdx.x >> 8;                    // 256 blocks per batch
    const int n0 = ((blockIdx.x & 255) << 4) | (wid << 2);
    const float4* pb = pts4 + ((size_t)b << 12);
    const float4 c0 = pb[n0], c1 = pb[n0 + 1], c2 = pb[n0 + 2], c3 = pb[n0 + 3];
    const float r2 = (float)(0.12 * 0.12);
    int first_val = -1;
    int t0 = 0, t1 = 0, t2 = 0, t3 = 0;
    bool e0 = false, e1 = false, e2 = false, e3 = false;

    for (int ch = 0; ch < 64; ++ch) {
        const int j = (ch << 6) | lane;
        const float4 p = pb[j];
#define CENTER(cc, CN, TK, DN)                                                               \
        if (!DN) {                                                                           \
            float dot = __fadd_rn(__fadd_rn(__fmul_rn(CN.x, p.x), __fmul_rn(CN.y, p.y)),     \
                                  __fmul_rn(CN.z, p.z));                                     \
            float dd = __fsub_rn(__fadd_rn(CN.w, p.w), __fmul_rn(2.0f, dot));                \
            bool ok = (dd <= r2) && (j != n0 + cc);                                          \
            unsigned long long m = __ballot(ok);                                             \
            if (m) {                                                                         \
                unsigned long long bx = __ballot(p.x >= CN.x);                               \
                unsigned long long by = __ballot(p.y >= CN.y);                               \
                unsigned long long bz = __ballot(p.z >= CN.z);                               \
                while (m) {                                                                  \
                    int t = __builtin_ctzll(m);                                              \
                    m &= m - 1;                                                              \
                    int oct = (int)((bx >> t) & 1) * 4 + (int)((by >> t) & 1) * 2            \
                            + (int)((bz >> t) & 1);                                          \
                    if (oct < 7 && lane == cc * 8 + oct && first_val < 0)                    \
                        first_val = (ch << 6) | t;                                           \
                    ++TK;                                                                    \
                    if (TK >= 31) break;                                                     \
                }                                                                            \
            }                                                                                \
        }
        CENTER(0, c0, t0, e0)
        CENTER(1, c1, t1, e1)
        CENTER(2, c2, t2, e2)
        CENTER(3, c3, t3, e3)
#undef CENTER
        unsigned long long fb = __ballot(first_val >= 0);
        e0 = (t0 >= 31) || (((fb >> 0)  & 0x7full) == 0x7full);
        e1 = (t1 >= 31) || (((fb >> 8)  & 0x7full) == 0x7full);
        e2 = (t2 >= 31) || (((fb >> 16) & 0x7full) == 0x7full);
        e3 = (t3 >= 31) || (((fb >> 24) & 0x7full) == 0x7full);
        if (e0 && e1 && e2 && e3) break;
    }

    const int cc = lane >> 3, oo = lane & 7;
    if (cc < 4) {
        size_t base = (((size_t)b << 12) | (size_t)(n0 + cc)) * 8;
        if (oo == 7) idx8[base] = n0 + cc;
        else idx8[base + 1 + oo] = (first_val < 0) ? N_PTS : first_val;
    }
}

// ---------------- kernel 2: transpose x [B,C,N] fp32 -> xbf [B][N+1][C] bf16 ----------
__global__ __launch_bounds__(256) void xpose_kernel(const float* __restrict__ x,
                                                    unsigned short* __restrict__ xbf) {
    __shared__ __attribute__((aligned(16))) unsigned short tile[64 * 132];
    const int tid = threadIdx.x;
    const int b = blockIdx.x / 65;
    const int j0 = (blockIdx.x % 65) * 64;
    if (j0 < N_PTS) {
        for (int c0 = 0; c0 < C_IN; c0 += 4) {
            int cc = c0 + (tid >> 6);
            int jj = tid & 63;
            float v = x[((size_t)b * C_IN + cc) * N_PTS + j0 + jj];
            tile[jj * 132 + cc] = f2bf(v);
        }
        __syncthreads();
        for (int i = 0; i < 8; ++i) {
            int idx = i * 256 + tid;          // 0..2047 -> 64 rows x 32 quads
            int row = idx >> 5, cq = idx & 31;
            uint2 v = *(const uint2*)&tile[row * 132 + cq * 4];
            *(uint2*)&xbf[((size_t)b * (N_PTS + 1) + j0 + row) * C_IN + cq * 4] = v;
        }
    } else {
        // zeros row j = 4096 (empty-octant gather target)
        for (int i = tid; i < C_IN; i += 256)
            xbf[((size_t)b * (N_PTS + 1) + N_PTS) * C_IN + i] = 0;
    }
}

// ---------------- kernel 3: gathered GEMM, bf16 MFMA 16x16x32 ----------------------
// D[o][n] = sum_kappa W[o][kappa] * P[n][kappa];  M-tile 64 points, N-tile 64 outs,
// BK=64, 4 waves each computing 32x32. LDS XOR-swizzle (slot ^= row&7) applied via
// pre-swizzled per-lane GLOBAL source (global_load_lds writes linearly) + swizzled read.
__global__ __launch_bounds__(256) void pconv_gemm(const unsigned short* __restrict__ xbf,
                                                  const unsigned short* __restrict__ wt,
                                                  const int* __restrict__ idx8,
                                                  const float* __restrict__ bias,
                                                  float* __restrict__ out) {
    __shared__ __attribute__((aligned(16))) unsigned short Plds[64 * 64];
    __shared__ __attribute__((aligned(16))) unsigned short Wlds[64 * 64];
    const int tid = threadIdx.x;
    const int tm = blockIdx.x >> 2, tn = blockIdx.x & 3;
    const int g0 = tm * 64;                  // global point-row base
    const int b  = g0 >> 12;
    const int nb = g0 & 4095;
    const int o0 = tn * 64;
    const int wid = tid >> 6, lane = tid & 63;
    const int wo = wid >> 1, wn = wid & 1;

    f32x4 acc[2][2] = {};

    for (int it = 0; it < 16; ++it) {
        const int k0 = it << 6;
        const int slot_id = k0 >> 7;         // which of the 8 gather slots
        const int cb = k0 & 127;             // channel base within slot
#pragma unroll
        for (int i = 0; i < 2; ++i) {
            const int Lb = i * 256 + wid * 64;          // wave-uniform 16B-slot base
            const int row = (Lb + lane) >> 3;           // tile row this lane feeds
            const int slog = (lane & 7) ^ (row & 7);    // pre-swizzled source slot
            // P: gathered point features
            int j = idx8[(size_t)(g0 + row) * 8 + slot_id];
            const unsigned short* psrc =
                xbf + ((size_t)b * (N_PTS + 1) + j) * C_IN + cb + slog * 8;
            gload_lds16(psrc, &Plds[Lb * 8]);
            // W: weight rows
            const unsigned short* wsrc =
                wt + (size_t)(o0 + row) * KDIM + k0 + slog * 8;
            gload_lds16(wsrc, &Wlds[Lb * 8]);
        }
        __syncthreads();
#pragma unroll
        for (int ks = 0; ks < 2; ++ks) {
            bf16x8 wf[2], pf[2];
#pragma unroll
            for (int f = 0; f < 2; ++f) {
                int orow = wo * 32 + f * 16 + (lane & 15);
                int slw = (ks * 4 + (lane >> 4)) ^ (orow & 7);
                wf[f] = *(const bf16x8*)&Wlds[orow * 64 + slw * 8];
                int nrow = wn * 32 + f * 16 + (lane & 15);
                int slp = (ks * 4 + (lane >> 4)) ^ (nrow & 7);
                pf[f] = *(const bf16x8*)&Plds[nrow * 64 + slp * 8];
            }
#pragma unroll
            for (int of = 0; of < 2; ++of)
#pragma unroll
                for (int nf = 0; nf < 2; ++nf)
                    acc[of][nf] = __builtin_amdgcn_mfma_f32_16x16x32_bf16(
                        wf[of], pf[nf], acc[of][nf], 0, 0, 0);
        }
        __syncthreads();
    }

#pragma unroll
    for (int of = 0; of < 2; ++of) {
        int o = o0 + wo * 32 + of * 16 + (lane >> 4) * 4;
#pragma unroll
        for (int nf = 0; nf < 2; ++nf) {
            int n = nb + wn * 32 + nf * 16 + (lane & 15);
#pragma unroll
            for (int r = 0; r < 4; ++r) {
                out[((size_t)b * C_OUT + o + r) * N_PTS + n] = acc[of][nf][r] + bias[o + r];
            }
        }
    }
}

extern "C" void kernel_launch(void* const* d_in, const int* in_sizes, int n_in,
                              void* d_out, int out_size, void* d_ws, size_t ws_size,
                              hipStream_t stream) {
    const float* x    = (const float*)d_in[0];
    const float* pcs  = (const float*)d_in[1];
    const float* w    = (const float*)d_in[2];
    const float* bias = (const float*)d_in[3];

    // ws layout: xbf [4*4097*128] bf16 | wt [256*1024] bf16 | idx8 [16384*8] int | pts4 [16384] float4
    unsigned short* xbf = (unsigned short*)d_ws;
    unsigned short* wt  = xbf + (size_t)BATCH * (N_PTS + 1) * C_IN;
    int* idx8 = (int*)(wt + (size_t)C_OUT * KDIM);
    float4* pts4 = (float4*)(idx8 + (size_t)BATCH * N_PTS * 8);
    float* out = (float*)d_out;

    hipLaunchKernelGGL(prep_kernel,  dim3(1088),       dim3(256), 0, stream, w, wt, pcs, pts4);
    hipLaunchKernelGGL(bq_kernel,    dim3(1024),       dim3(256), 0, stream, pts4, idx8);
    hipLaunchKernelGGL(xpose_kernel, dim3(BATCH * 65), dim3(256), 0, stream, x, xbf);
    hipLaunchKernelGGL(pconv_gemm,   dim3(1024),       dim3(256), 0, stream,
                       xbf, wt, idx8, bias, out);
}

// Round 3
// 87.347 us; speedup vs baseline: 1.4954x; 1.0679x over previous
//
#include <hip/hip_runtime.h>
#include <stdint.h>

#define N_PTS 4096
#define BATCH 4
#define C_IN  128
#define C_OUT 256
#define KDIM  1024   // 8 active slots * 128 channels (octant-7 slot is provably always zero)

typedef __attribute__((ext_vector_type(8))) __bf16 bf16x8;
typedef __attribute__((ext_vector_type(4))) float  f32x4;

__device__ inline void gload_lds16(const void* g, void* l) {
    __builtin_amdgcn_global_load_lds(
        (__attribute__((address_space(1))) void*)(void*)(uintptr_t)g,
        (__attribute__((address_space(3))) void*)l, 16, 0, 0);
}

__device__ inline unsigned short f2bf(float v) {
    uint32_t u = __builtin_bit_cast(uint32_t, v);
    return (unsigned short)((u + 0x7fffu + ((u >> 16) & 1u)) >> 16);   // RTNE
}

// ---------------- kernel 0: prep — weight transpose + packed pts4 ----------------
__global__ __launch_bounds__(256) void prep_kernel(const float* __restrict__ w,
                                                   unsigned short* __restrict__ wt,
                                                   const float* __restrict__ pcs,
                                                   float4* __restrict__ pts4) {
    const int bid = blockIdx.x;
    if (bid < 1024) {
        int gidx = bid * 256 + threadIdx.x;           // 0..262143
        int o = gidx >> 10, k = gidx & 1023;
        int slot = k >> 7, cch = k & 127;             // slot 0=center, slot s=octant s-1
        wt[gidx] = f2bf(w[(size_t)o * 1152 + cch * 9 + slot]);
    } else {
        int i = (bid - 1024) * 256 + threadIdx.x;     // 0..16383
        int b = i >> 12, n = i & 4095;
        const float* pb = pcs + (size_t)b * 3 * N_PTS;
        float x = pb[n], y = pb[N_PTS + n], z = pb[2 * N_PTS + n];
        // match reference: sq = ((x*x + y*y) + z*z), no FMA contraction
        float sq = __fadd_rn(__fadd_rn(__fmul_rn(x, x), __fmul_rn(y, y)), __fmul_rn(z, z));
        pts4[i] = make_float4(x, y, z, sq);
    }
}

// ---------------- kernel 1: ball query + per-octant first neighbor ----------------
// 4 centers per wave, no LDS, no serial per-match loop: matches are consumed via
// wave-uniform mask algebra (octant masks from sign ballots + ctz), the 31-cap via
// popcount + top-bit truncation at the crossing chunk (== ascending-order consume).
// 2-chunk unroll with prefetch hides L2 latency under VALU.
__global__ __launch_bounds__(256) void bq_kernel(const float4* __restrict__ pts4,
                                                 int* __restrict__ idx8) {
    const int tid = threadIdx.x;
    const int wid = tid >> 6, lane = tid & 63;
    const int b = blockIdx.x >> 8;                    // 256 blocks per batch
    const int n0 = ((blockIdx.x & 255) << 4) | (wid << 2);
    const float4* pb = pts4 + ((size_t)b << 12);
    const float4 c0 = pb[n0], c1 = pb[n0 + 1], c2 = pb[n0 + 2], c3 = pb[n0 + 3];
    const float r2 = (float)(0.12 * 0.12);

#define DECL_CENTER(i)                                                              \
    int cnt##i = 0; bool done##i = false;                                           \
    int f##i##0 = -1, f##i##1 = -1, f##i##2 = -1, f##i##3 = -1, f##i##4 = -1,       \
        f##i##5 = -1, f##i##6 = -1;
    DECL_CENTER(0) DECL_CENTER(1) DECL_CENTER(2) DECL_CENTER(3)

#define OCT_UPD(i, o, EXPR)                                                         \
    if (f##i##o < 0) {                                                              \
        unsigned long long mo_ = m & (EXPR);                                        \
        if (mo_) f##i##o = jb + __builtin_ctzll(mo_);                               \
    }

#define PROC_CENTER(i, CN)                                                          \
    if (!done##i) {                                                                 \
        float dot = __fadd_rn(__fadd_rn(__fmul_rn(CN.x, p.x), __fmul_rn(CN.y, p.y)),\
                              __fmul_rn(CN.z, p.z));                                \
        float dd = __fsub_rn(__fadd_rn(CN.w, p.w), __fmul_rn(2.0f, dot));           \
        bool ok = (dd <= r2) && (j != n0 + i);                                      \
        unsigned long long m = __ballot(ok);                                        \
        if (m) {                                                                    \
            unsigned long long bx = __ballot(p.x >= CN.x);                          \
            unsigned long long by = __ballot(p.y >= CN.y);                          \
            unsigned long long bz = __ballot(p.z >= CN.z);                          \
            int pc = __builtin_popcountll(m);                                       \
            if (cnt##i + pc > 31) {                                                 \
                int drop = cnt##i + pc - 31;                                        \
                for (int d_ = 0; d_ < drop; ++d_)                                   \
                    m &= ~(1ull << (63 - __builtin_clzll(m)));                      \
                pc = 31 - cnt##i;                                                   \
            }                                                                       \
            cnt##i += pc;                                                           \
            unsigned long long nbx = ~bx, nby = ~by, nbz = ~bz;                     \
            OCT_UPD(i, 0, nbx & nby & nbz)                                          \
            OCT_UPD(i, 1, nbx & nby & bz)                                           \
            OCT_UPD(i, 2, nbx & by  & nbz)                                          \
            OCT_UPD(i, 3, nbx & by  & bz)                                           \
            OCT_UPD(i, 4, bx  & nby & nbz)                                          \
            OCT_UPD(i, 5, bx  & nby & bz)                                           \
            OCT_UPD(i, 6, bx  & by  & nbz)                                          \
            done##i = (cnt##i >= 31) ||                                             \
                      ((f##i##0 | f##i##1 | f##i##2 | f##i##3 | f##i##4 |           \
                        f##i##5 | f##i##6) >= 0);                                   \
        }                                                                           \
    }

#define PROC_CHUNK(PV, JB)                                                          \
    {                                                                               \
        const float4 p = PV;                                                        \
        const int jb = (JB);                                                        \
        const int j = jb | lane;                                                    \
        PROC_CENTER(0, c0) PROC_CENTER(1, c1) PROC_CENTER(2, c2) PROC_CENTER(3, c3) \
    }

    float4 pA = pb[lane];
    float4 pB = pb[64 | lane];
    for (int ch = 0; ch < 64; ch += 2) {
        float4 pC = pb[(((ch + 2) & 63) << 6) | lane];
        float4 pD = pb[(((ch + 3) & 63) << 6) | lane];
        PROC_CHUNK(pA, ch << 6)
        PROC_CHUNK(pB, (ch + 1) << 6)
        if (done0 && done1 && done2 && done3) break;
        pA = pC; pB = pD;
    }

    // write-out: 32 consecutive ints (center idx + 7 octant firsts, x4 centers)
    const int cc = lane >> 3, s = lane & 7;
    int v = n0 + cc;                                  // s==0: center index
#define PICK(i, o) if (cc == i && s == 1 + o) v = (f##i##o < 0) ? N_PTS : f##i##o;
#define PICK7(i) PICK(i,0) PICK(i,1) PICK(i,2) PICK(i,3) PICK(i,4) PICK(i,5) PICK(i,6)
    PICK7(0) PICK7(1) PICK7(2) PICK7(3)
#undef PICK
#undef PICK7
    if (lane < 32) idx8[(((size_t)b << 12) + n0) * 8 + lane] = v;
}

// ---------------- kernel 2: transpose x [B,C,N] fp32 -> xbf [B][N+1][C] bf16 ----------
__global__ __launch_bounds__(256) void xpose_kernel(const float* __restrict__ x,
                                                    unsigned short* __restrict__ xbf) {
    __shared__ __attribute__((aligned(16))) unsigned short tile[64 * 132];
    const int tid = threadIdx.x;
    const int b = blockIdx.x / 65;
    const int j0 = (blockIdx.x % 65) * 64;
    if (j0 < N_PTS) {
        for (int c0 = 0; c0 < C_IN; c0 += 4) {
            int cc = c0 + (tid >> 6);
            int jj = tid & 63;
            float v = x[((size_t)b * C_IN + cc) * N_PTS + j0 + jj];
            tile[jj * 132 + cc] = f2bf(v);
        }
        __syncthreads();
        for (int i = 0; i < 8; ++i) {
            int idx = i * 256 + tid;          // 0..2047 -> 64 rows x 32 quads
            int row = idx >> 5, cq = idx & 31;
            uint2 v = *(const uint2*)&tile[row * 132 + cq * 4];
            *(uint2*)&xbf[((size_t)b * (N_PTS + 1) + j0 + row) * C_IN + cq * 4] = v;
        }
    } else {
        // zeros row j = 4096 (empty-octant gather target)
        for (int i = tid; i < C_IN; i += 256)
            xbf[((size_t)b * (N_PTS + 1) + N_PTS) * C_IN + i] = 0;
    }
}

// ---------------- kernel 3: gathered GEMM, bf16 MFMA 16x16x32 ----------------------
__global__ __launch_bounds__(256) void pconv_gemm(const unsigned short* __restrict__ xbf,
                                                  const unsigned short* __restrict__ wt,
                                                  const int* __restrict__ idx8,
                                                  const float* __restrict__ bias,
                                                  float* __restrict__ out) {
    __shared__ __attribute__((aligned(16))) unsigned short Plds[64 * 64];
    __shared__ __attribute__((aligned(16))) unsigned short Wlds[64 * 64];
    const int tid = threadIdx.x;
    const int tm = blockIdx.x >> 2, tn = blockIdx.x & 3;
    const int g0 = tm * 64;                  // global point-row base
    const int b  = g0 >> 12;
    const int nb = g0 & 4095;
    const int o0 = tn * 64;
    const int wid = tid >> 6, lane = tid & 63;
    const int wo = wid >> 1, wn = wid & 1;

    f32x4 acc[2][2] = {};

    for (int it = 0; it < 16; ++it) {
        const int k0 = it << 6;
        const int slot_id = k0 >> 7;         // which of the 8 gather slots
        const int cb = k0 & 127;             // channel base within slot
#pragma unroll
        for (int i = 0; i < 2; ++i) {
            const int Lb = i * 256 + wid * 64;          // wave-uniform 16B-slot base
            const int row = (Lb + lane) >> 3;           // tile row this lane feeds
            const int slog = (lane & 7) ^ (row & 7);    // pre-swizzled source slot
            // P: gathered point features
            int j = idx8[(size_t)(g0 + row) * 8 + slot_id];
            const unsigned short* psrc =
                xbf + ((size_t)b * (N_PTS + 1) + j) * C_IN + cb + slog * 8;
            gload_lds16(psrc, &Plds[Lb * 8]);
            // W: weight rows
            const unsigned short* wsrc =
                wt + (size_t)(o0 + row) * KDIM + k0 + slog * 8;
            gload_lds16(wsrc, &Wlds[Lb * 8]);
        }
        __syncthreads();
#pragma unroll
        for (int ks = 0; ks < 2; ++ks) {
            bf16x8 wf[2], pf[2];
#pragma unroll
            for (int f = 0; f < 2; ++f) {
                int orow = wo * 32 + f * 16 + (lane & 15);
                int slw = (ks * 4 + (lane >> 4)) ^ (orow & 7);
                wf[f] = *(const bf16x8*)&Wlds[orow * 64 + slw * 8];
                int nrow = wn * 32 + f * 16 + (lane & 15);
                int slp = (ks * 4 + (lane >> 4)) ^ (nrow & 7);
                pf[f] = *(const bf16x8*)&Plds[nrow * 64 + slp * 8];
            }
#pragma unroll
            for (int of = 0; of < 2; ++of)
#pragma unroll
                for (int nf = 0; nf < 2; ++nf)
                    acc[of][nf] = __builtin_amdgcn_mfma_f32_16x16x32_bf16(
                        wf[of], pf[nf], acc[of][nf], 0, 0, 0);
        }
        __syncthreads();
    }

#pragma unroll
    for (int of = 0; of < 2; ++of) {
        int o = o0 + wo * 32 + of * 16 + (lane >> 4) * 4;
#pragma unroll
        for (int nf = 0; nf < 2; ++nf) {
            int n = nb + wn * 32 + nf * 16 + (lane & 15);
#pragma unroll
            for (int r = 0; r < 4; ++r) {
                out[((size_t)b * C_OUT + o + r) * N_PTS + n] = acc[of][nf][r] + bias[o + r];
            }
        }
    }
}

extern "C" void kernel_launch(void* const* d_in, const int* in_sizes, int n_in,
                              void* d_out, int out_size, void* d_ws, size_t ws_size,
                              hipStream_t stream) {
    const float* x    = (const float*)d_in[0];
    const float* pcs  = (const float*)d_in[1];
    const float* w    = (const float*)d_in[2];
    const float* bias = (const float*)d_in[3];

    // ws layout: xbf [4*4097*128] bf16 | wt [256*1024] bf16 | idx8 [16384*8] int | pts4 [16384] float4
    unsigned short* xbf = (unsigned short*)d_ws;
    unsigned short* wt  = xbf + (size_t)BATCH * (N_PTS + 1) * C_IN;
    int* idx8 = (int*)(wt + (size_t)C_OUT * KDIM);
    float4* pts4 = (float4*)(idx8 + (size_t)BATCH * N_PTS * 8);
    float* out = (float*)d_out;

    hipLaunchKernelGGL(prep_kernel,  dim3(1088),       dim3(256), 0, stream, w, wt, pcs, pts4);
    hipLaunchKernelGGL(bq_kernel,    dim3(1024),       dim3(256), 0, stream, pts4, idx8);
    hipLaunchKernelGGL(xpose_kernel, dim3(BATCH * 65), dim3(256), 0, stream, x, xbf);
    hipLaunchKernelGGL(pconv_gemm,   dim3(1024),       dim3(256), 0, stream,
                       xbf, wt, idx8, bias, out);
}

// Round 5
// 66.568 us; speedup vs baseline: 1.9622x; 1.3122x over previous
//
#include <hip/hip_runtime.h>
#include <stdint.h>

#define N_PTS 4096
#define BATCH 4
#define C_IN  128
#define C_OUT 256
#define KDIM  1024   // 8 active slots * 128 channels (octant-7 slot provably always zero)
#define NCELL 512    // 8x8x8 spatial grid, cell 0.125 >= radius 0.12
#define BIGJ  0x3fffffff

typedef __attribute__((ext_vector_type(8))) __bf16 bf16x8;
typedef __attribute__((ext_vector_type(4))) float  f32x4;

__device__ inline void gload_lds16(const void* g, void* l) {
    __builtin_amdgcn_global_load_lds(
        (__attribute__((address_space(1))) void*)(void*)(uintptr_t)g,
        (__attribute__((address_space(3))) void*)l, 16, 0, 0);
}

__device__ inline unsigned short f2bf(float v) {
    uint32_t u = __builtin_bit_cast(uint32_t, v);
    return (unsigned short)((u + 0x7fffu + ((u >> 16) & 1u)) >> 16);   // RTNE
}

// reference-exact sq = ((x*x + y*y) + z*z), no FMA contraction
__device__ inline float sq_exact(float x, float y, float z) {
    return __fadd_rn(__fadd_rn(__fmul_rn(x, x), __fmul_rn(y, y)), __fmul_rn(z, z));
}

__device__ inline int cell_of(float x, float y, float z) {
    int cx = (int)(x * 8.0f); cx = min(max(cx, 0), 7);
    int cy = (int)(y * 8.0f); cy = min(max(cy, 0), 7);
    int cz = (int)(z * 8.0f); cz = min(max(cz, 0), 7);
    return (cx << 6) | (cy << 3) | cz;
}

__device__ inline int wmin(int v) {
    for (int off = 32; off >= 1; off >>= 1) v = min(v, __shfl_xor(v, off, 64));
    return v;
}

// ---------------- kernel 0: prep — wt transpose + zero cell counters ----------------
__global__ __launch_bounds__(256) void prep_kernel(const float* __restrict__ w,
                                                   unsigned short* __restrict__ wt,
                                                   int* __restrict__ cellA) {
    const int bid = blockIdx.x;
    if (bid < 1024) {
        int gidx = bid * 256 + threadIdx.x;           // 0..262143
        int o = gidx >> 10, k = gidx & 1023;
        int slot = k >> 7, cch = k & 127;             // slot 0=center, slot s=octant s-1
        wt[gidx] = f2bf(w[(size_t)o * 1152 + cch * 9 + slot]);
    } else {
        int i = (bid - 1024) * 256 + threadIdx.x;     // 0..2047 == BATCH*NCELL
        cellA[i] = 0;
    }
}

// ---------------- kernel 1: count points per cell ----------------
__global__ __launch_bounds__(256) void count_kernel(const float* __restrict__ pcs,
                                                    int* __restrict__ cellA) {
    int i = blockIdx.x * 256 + threadIdx.x;           // 0..16383
    int b = i >> 12, n = i & 4095;
    const float* pb = pcs + (size_t)b * 3 * N_PTS;
    atomicAdd(&cellA[b * NCELL + cell_of(pb[n], pb[N_PTS + n], pb[2 * N_PTS + n])], 1);
}

// ---------------- kernel 2: exclusive prefix per batch (512 cells) ----------------
// Overwrites cellA in place with the exclusive prefix (becomes scatter cursor).
__global__ __launch_bounds__(512) void prefix_kernel(int* __restrict__ cellA,
                                                     int* __restrict__ cellstart) {
    __shared__ int sbuf[512];
    const int b = blockIdx.x, t = threadIdx.x;
    int v = cellA[b * NCELL + t];
    sbuf[t] = v;
    __syncthreads();
    for (int off = 1; off < 512; off <<= 1) {
        int tv = (t >= off) ? sbuf[t - off] : 0;
        __syncthreads();
        sbuf[t] += tv;
        __syncthreads();
    }
    int excl = sbuf[t] - v;
    cellstart[b * 513 + t] = excl;
    cellA[b * NCELL + t] = excl;
    if (t == 511) cellstart[b * 513 + 512] = sbuf[511];
}

// ---------------- kernel 3: scatter points into cell-sorted array ----------------
// sp4[slot] = (x, y, z, bitcast(original index j))
__global__ __launch_bounds__(256) void scatter_kernel(const float* __restrict__ pcs,
                                                      int* __restrict__ cellA,
                                                      float4* __restrict__ sp4) {
    int i = blockIdx.x * 256 + threadIdx.x;           // 0..16383
    int b = i >> 12, n = i & 4095;
    const float* pb = pcs + (size_t)b * 3 * N_PTS;
    float x = pb[n], y = pb[N_PTS + n], z = pb[2 * N_PTS + n];
    int slot = atomicAdd(&cellA[b * NCELL + cell_of(x, y, z)], 1);
    float4 v = make_float4(x, y, z, __builtin_bit_cast(float, n));
    sp4[(b << 12) + slot] = v;
}

// ---------------- kernel 4: grid ball query — one wave per center ----------------
// Scans the 27-cell neighborhood. Per-lane octant-min (order-free); cap via T =
// 31st-smallest match index (in-wave bitonic sort of the complete match set when
// cnt > 31) -> deterministic under arbitrary within-cell scatter order.
__global__ __launch_bounds__(256) void bq_grid(const float* __restrict__ pcs,
                                               const float4* __restrict__ sp4,
                                               const int* __restrict__ cellstart,
                                               unsigned short* __restrict__ idxu) {
    __shared__ int lists[4 * 128];
    const int tid = threadIdx.x;
    const int wid = tid >> 6, lane = tid & 63;
    const int b = blockIdx.x >> 10;                   // 1024 blocks per batch
    const int n = ((blockIdx.x & 1023) << 2) | wid;
    const int g = (b << 12) | n;
    const float* pb = pcs + (size_t)b * 3 * N_PTS;
    const float cxf = pb[n], cyf = pb[N_PTS + n], czf = pb[2 * N_PTS + n];
    const float csq = sq_exact(cxf, cyf, czf);
    const float4* sp = sp4 + ((size_t)b << 12);
    const int* cs = cellstart + b * 513;
    const float r2 = (float)(0.12 * 0.12);

    int cx = min(max((int)(cxf * 8.0f), 0), 7);
    int cy = min(max((int)(cyf * 8.0f), 0), 7);
    int cz = min(max((int)(czf * 8.0f), 0), 7);
    const int xlo = max(cx - 1, 0), xhi = min(cx + 1, 7);
    const int ylo = max(cy - 1, 0), yhi = min(cy + 1, 7);
    const int zlo = max(cz - 1, 0), zhi = min(cz + 1, 7);

    int f0 = BIGJ, f1 = BIGJ, f2 = BIGJ, f3 = BIGJ, f4 = BIGJ, f5 = BIGJ, f6 = BIGJ;
    int cnt = 0;
    int* lst = &lists[wid * 128];
    const unsigned long long ltm = (1ull << lane) - 1ull;

    for (int gx = xlo; gx <= xhi; ++gx)
        for (int gy = ylo; gy <= yhi; ++gy) {
            const int cb = (gx << 6) | (gy << 3);
            const int rs = cs[cb + zlo], re = cs[cb + zhi + 1];
            for (int s0 = rs; s0 < re; s0 += 64) {
                const int i = s0 + lane;
                const bool valid = i < re;
                const int ic = valid ? i : rs;
                const float4 p = sp[ic];
                const int j = __builtin_bit_cast(int, p.w);
                const float psq = sq_exact(p.x, p.y, p.z);   // bit-identical to reference
                float dot = __fadd_rn(__fadd_rn(__fmul_rn(cxf, p.x), __fmul_rn(cyf, p.y)),
                                      __fmul_rn(czf, p.z));
                float dd = __fsub_rn(__fadd_rn(csq, psq), __fmul_rn(2.0f, dot));
                const bool ok = valid && (dd <= r2) && (j != n);
                unsigned long long m = __ballot(ok);
                if (m) {
                    int pos = cnt + __popcll(m & ltm);
                    if (ok && pos < 128) lst[pos] = j;
                    cnt += __popcll(m);
                    const int oct = ((p.x >= cxf) ? 4 : 0) + ((p.y >= cyf) ? 2 : 0)
                                  + ((p.z >= czf) ? 1 : 0);
                    const int key = ok ? j : BIGJ;
                    f0 = (oct == 0) ? min(f0, key) : f0;
                    f1 = (oct == 1) ? min(f1, key) : f1;
                    f2 = (oct == 2) ? min(f2, key) : f2;
                    f3 = (oct == 3) ? min(f3, key) : f3;
                    f4 = (oct == 4) ? min(f4, key) : f4;
                    f5 = (oct == 5) ? min(f5, key) : f5;
                    f6 = (oct == 6) ? min(f6, key) : f6;
                }
            }
        }

    f0 = wmin(f0); f1 = wmin(f1); f2 = wmin(f2); f3 = wmin(f3);
    f4 = wmin(f4); f5 = wmin(f5); f6 = wmin(f6);

    if (cnt > 31) {
        // pad to 128, bitonic sort ascending, T = 31st smallest match index
        const int c2 = min(cnt, 128);
        for (int i2 = lane; i2 < 128; i2 += 64)
            if (i2 >= c2) lst[i2] = BIGJ;
        for (int k = 2; k <= 128; k <<= 1)
            for (int st = k >> 1; st > 0; st >>= 1) {
                const int idx = (lane & (st - 1)) | ((lane & ~(st - 1)) << 1);
                const int par = idx | st;
                const bool up = ((idx & k) == 0);
                int a = lst[idx], bb = lst[par];
                if ((a > bb) == up) { lst[idx] = bb; lst[par] = a; }
            }
        const int T = lst[30];
        f0 = (f0 <= T) ? f0 : BIGJ;
        f1 = (f1 <= T) ? f1 : BIGJ;
        f2 = (f2 <= T) ? f2 : BIGJ;
        f3 = (f3 <= T) ? f3 : BIGJ;
        f4 = (f4 <= T) ? f4 : BIGJ;
        f5 = (f5 <= T) ? f5 : BIGJ;
        f6 = (f6 <= T) ? f6 : BIGJ;
    }

    int v = n;                                        // lane 0: center index
    if (lane == 1) v = f0;
    if (lane == 2) v = f1;
    if (lane == 3) v = f2;
    if (lane == 4) v = f3;
    if (lane == 5) v = f4;
    if (lane == 6) v = f5;
    if (lane == 7) v = f6;
    if (v > N_PTS) v = N_PTS;                         // BIGJ -> zeros row
    if (lane < 8) idxu[(size_t)g * 8 + lane] = (unsigned short)v;
}

// ---------------- kernel 5: transpose x [B,C,N] fp32 -> xbf [B][N+1][C] bf16 ----------
__global__ __launch_bounds__(256) void xpose_kernel(const float* __restrict__ x,
                                                    unsigned short* __restrict__ xbf) {
    __shared__ __attribute__((aligned(16))) unsigned short tile[64 * 132];
    const int tid = threadIdx.x;
    const int b = blockIdx.x / 65;
    const int j0 = (blockIdx.x % 65) * 64;
    if (j0 < N_PTS) {
        for (int c0 = 0; c0 < C_IN; c0 += 4) {
            int cc = c0 + (tid >> 6);
            int jj = tid & 63;
            float v = x[((size_t)b * C_IN + cc) * N_PTS + j0 + jj];
            tile[jj * 132 + cc] = f2bf(v);
        }
        __syncthreads();
        for (int i = 0; i < 8; ++i) {
            int idx = i * 256 + tid;          // 0..2047 -> 64 rows x 32 quads
            int row = idx >> 5, cq = idx & 31;
            uint2 v = *(const uint2*)&tile[row * 132 + cq * 4];
            *(uint2*)&xbf[((size_t)b * (N_PTS + 1) + j0 + row) * C_IN + cq * 4] = v;
        }
    } else {
        // zeros row j = 4096 (empty-octant gather target)
        for (int i = tid; i < C_IN; i += 256)
            xbf[((size_t)b * (N_PTS + 1) + N_PTS) * C_IN + i] = 0;
    }
}

// ---------------- kernel 6: gathered GEMM, bf16 MFMA 16x16x32 ----------------------
__global__ __launch_bounds__(256) void pconv_gemm(const unsigned short* __restrict__ xbf,
                                                  const unsigned short* __restrict__ wt,
                                                  const unsigned short* __restrict__ idxu,
                                                  const float* __restrict__ bias,
                                                  float* __restrict__ out) {
    __shared__ __attribute__((aligned(16))) unsigned short Plds[64 * 64];
    __shared__ __attribute__((aligned(16))) unsigned short Wlds[64 * 64];
    const int tid = threadIdx.x;
    const int tm = blockIdx.x >> 2, tn = blockIdx.x & 3;
    const int g0 = tm * 64;                  // global point-row base
    const int b  = g0 >> 12;
    const int nb = g0 & 4095;
    const int o0 = tn * 64;
    const int wid = tid >> 6, lane = tid & 63;
    const int wo = wid >> 1, wn = wid & 1;

    f32x4 acc[2][2] = {};

    for (int it = 0; it < 16; ++it) {
        const int k0 = it << 6;
        const int slot_id = k0 >> 7;         // which of the 8 gather slots
        const int cb = k0 & 127;             // channel base within slot
#pragma unroll
        for (int i = 0; i < 2; ++i) {
            const int Lb = i * 256 + wid * 64;          // wave-uniform 16B-slot base
            const int row = (Lb + lane) >> 3;           // tile row this lane feeds
            const int slog = (lane & 7) ^ (row & 7);    // pre-swizzled source slot
            // P: gathered point features
            int j = idxu[(size_t)(g0 + row) * 8 + slot_id];
            const unsigned short* psrc =
                xbf + ((size_t)b * (N_PTS + 1) + j) * C_IN + cb + slog * 8;
            gload_lds16(psrc, &Plds[Lb * 8]);
            // W: weight rows
            const unsigned short* wsrc =
                wt + (size_t)(o0 + row) * KDIM + k0 + slog * 8;
            gload_lds16(wsrc, &Wlds[Lb * 8]);
        }
        __syncthreads();
#pragma unroll
        for (int ks = 0; ks < 2; ++ks) {
            bf16x8 wf[2], pf[2];
#pragma unroll
            for (int f = 0; f < 2; ++f) {
                int orow = wo * 32 + f * 16 + (lane & 15);
                int slw = (ks * 4 + (lane >> 4)) ^ (orow & 7);
                wf[f] = *(const bf16x8*)&Wlds[orow * 64 + slw * 8];
                int nrow = wn * 32 + f * 16 + (lane & 15);
                int slp = (ks * 4 + (lane >> 4)) ^ (nrow & 7);
                pf[f] = *(const bf16x8*)&Plds[nrow * 64 + slp * 8];
            }
#pragma unroll
            for (int of = 0; of < 2; ++of)
#pragma unroll
                for (int nf = 0; nf < 2; ++nf)
                    acc[of][nf] = __builtin_amdgcn_mfma_f32_16x16x32_bf16(
                        wf[of], pf[nf], acc[of][nf], 0, 0, 0);
        }
        __syncthreads();
    }

#pragma unroll
    for (int of = 0; of < 2; ++of) {
        int o = o0 + wo * 32 + of * 16 + (lane >> 4) * 4;
#pragma unroll
        for (int nf = 0; nf < 2; ++nf) {
            int n = nb + wn * 32 + nf * 16 + (lane & 15);
#pragma unroll
            for (int r = 0; r < 4; ++r) {
                out[((size_t)b * C_OUT + o + r) * N_PTS + n] = acc[of][nf][r] + bias[o + r];
            }
        }
    }
}

extern "C" void kernel_launch(void* const* d_in, const int* in_sizes, int n_in,
                              void* d_out, int out_size, void* d_ws, size_t ws_size,
                              hipStream_t stream) {
    const float* x    = (const float*)d_in[0];
    const float* pcs  = (const float*)d_in[1];
    const float* w    = (const float*)d_in[2];
    const float* bias = (const float*)d_in[3];

    // ws layout (bytes) — total 5,260,304 < 5,506,048 proven-safe (rounds 1-3):
    char* base = (char*)d_ws;
    float4* sp4 = (float4*)base;                                    //       0 (262,144)
    unsigned short* xbf = (unsigned short*)(base + 262144);         // 4,195,328
    unsigned short* wt  = (unsigned short*)(base + 4457472);        //   524,288
    unsigned short* idxu = (unsigned short*)(base + 4981760);       //   262,144
    int* cellA     = (int*)(base + 5243904);                        //     8,192 (cnt->cursor)
    int* cellstart = (int*)(base + 5252096);                        //     8,208
    float* out = (float*)d_out;

    hipLaunchKernelGGL(prep_kernel,    dim3(1032),       dim3(256), 0, stream, w, wt, cellA);
    hipLaunchKernelGGL(count_kernel,   dim3(64),         dim3(256), 0, stream, pcs, cellA);
    hipLaunchKernelGGL(prefix_kernel,  dim3(BATCH),      dim3(512), 0, stream,
                       cellA, cellstart);
    hipLaunchKernelGGL(scatter_kernel, dim3(64),         dim3(256), 0, stream,
                       pcs, cellA, sp4);
    hipLaunchKernelGGL(bq_grid,        dim3(4096),       dim3(256), 0, stream,
                       pcs, sp4, cellstart, idxu);
    hipLaunchKernelGGL(xpose_kernel,   dim3(BATCH * 65), dim3(256), 0, stream, x, xbf);
    hipLaunchKernelGGL(pconv_gemm,     dim3(1024),       dim3(256), 0, stream,
                       xbf, wt, idxu, bias, out);
}

// Round 6
// 59.686 us; speedup vs baseline: 2.1884x; 1.1153x over previous
//
#include <hip/hip_runtime.h>
#include <stdint.h>

#define N_PTS 4096
#define BATCH 4
#define C_IN  128
#define C_OUT 256
#define KDIM  1024   // 8 active slots * 128 channels (octant-7 slot provably always zero)
#define NCELL 512    // 8x8x8 spatial grid, cell 0.125 >= radius 0.12
#define BIGJ  0x3fffffff

typedef __attribute__((ext_vector_type(8))) __bf16 bf16x8;
typedef __attribute__((ext_vector_type(4))) float  f32x4;

__device__ inline void gload_lds16(const void* g, void* l) {
    __builtin_amdgcn_global_load_lds(
        (__attribute__((address_space(1))) void*)(void*)(uintptr_t)g,
        (__attribute__((address_space(3))) void*)l, 16, 0, 0);
}

__device__ inline unsigned short f2bf(float v) {
    uint32_t u = __builtin_bit_cast(uint32_t, v);
    return (unsigned short)((u + 0x7fffu + ((u >> 16) & 1u)) >> 16);   // RTNE
}

// reference-exact sq = ((x*x + y*y) + z*z), no FMA contraction
__device__ inline float sq_exact(float x, float y, float z) {
    return __fadd_rn(__fadd_rn(__fmul_rn(x, x), __fmul_rn(y, y)), __fmul_rn(z, z));
}

__device__ inline int cell_of(float x, float y, float z) {
    int cx = (int)(x * 8.0f); cx = min(max(cx, 0), 7);
    int cy = (int)(y * 8.0f); cy = min(max(cy, 0), 7);
    int cz = (int)(z * 8.0f); cz = min(max(cz, 0), 7);
    return (cx << 6) | (cy << 3) | cz;
}

__device__ inline int wmin(int v) {
    for (int off = 32; off >= 1; off >>= 1) v = min(v, __shfl_xor(v, off, 64));
    return v;
}

// ---------------- kernel 0: prep — wt transpose + zero cell counters ----------------
__global__ __launch_bounds__(256) void prep_kernel(const float* __restrict__ w,
                                                   unsigned short* __restrict__ wt,
                                                   int* __restrict__ cellA) {
    const int bid = blockIdx.x;
    if (bid < 1024) {
        int gidx = bid * 256 + threadIdx.x;           // 0..262143
        int o = gidx >> 10, k = gidx & 1023;
        int slot = k >> 7, cch = k & 127;             // slot 0=center, slot s=octant s-1
        wt[gidx] = f2bf(w[(size_t)o * 1152 + cch * 9 + slot]);
    } else {
        int i = (bid - 1024) * 256 + threadIdx.x;     // 0..2047 == BATCH*NCELL
        cellA[i] = 0;
    }
}

// ---------------- kernel 1: count points per cell ----------------
__global__ __launch_bounds__(256) void count_kernel(const float* __restrict__ pcs,
                                                    int* __restrict__ cellA) {
    int i = blockIdx.x * 256 + threadIdx.x;           // 0..16383
    int b = i >> 12, n = i & 4095;
    const float* pb = pcs + (size_t)b * 3 * N_PTS;
    atomicAdd(&cellA[b * NCELL + cell_of(pb[n], pb[N_PTS + n], pb[2 * N_PTS + n])], 1);
}

// ---------------- kernel 2: exclusive prefix per batch (512 cells) ----------------
// Overwrites cellA in place with the exclusive prefix (becomes scatter cursor).
__global__ __launch_bounds__(512) void prefix_kernel(int* __restrict__ cellA,
                                                     int* __restrict__ cellstart) {
    __shared__ int sbuf[512];
    const int b = blockIdx.x, t = threadIdx.x;
    int v = cellA[b * NCELL + t];
    sbuf[t] = v;
    __syncthreads();
    for (int off = 1; off < 512; off <<= 1) {
        int tv = (t >= off) ? sbuf[t - off] : 0;
        __syncthreads();
        sbuf[t] += tv;
        __syncthreads();
    }
    int excl = sbuf[t] - v;
    cellstart[b * 513 + t] = excl;
    cellA[b * NCELL + t] = excl;
    if (t == 511) cellstart[b * 513 + 512] = sbuf[511];
}

// ---------------- kernel 3: scatter points into cell-sorted array ----------------
// sp4[slot] = (x, y, z, bitcast(original index j))
__global__ __launch_bounds__(256) void scatter_kernel(const float* __restrict__ pcs,
                                                      int* __restrict__ cellA,
                                                      float4* __restrict__ sp4) {
    int i = blockIdx.x * 256 + threadIdx.x;           // 0..16383
    int b = i >> 12, n = i & 4095;
    const float* pb = pcs + (size_t)b * 3 * N_PTS;
    float x = pb[n], y = pb[N_PTS + n], z = pb[2 * N_PTS + n];
    int slot = atomicAdd(&cellA[b * NCELL + cell_of(x, y, z)], 1);
    float4 v = make_float4(x, y, z, __builtin_bit_cast(float, n));
    sp4[(b << 12) + slot] = v;
}

// ---------------- kernel 4: grid ball query — one wave per center ----------------
// The 9 z-column runs of the 27-cell neighborhood are merged into ONE candidate
// stream (wave-uniform run table + per-lane cndmask chain) -> ~4 full 64-lane
// chunks instead of 9 sparse ones, coalesced loads. Octant firsts are order-free
// mins; 31-cap via rank check: f_o survives iff #{matches j < f_o} <= 30
// (== "f_o among the 31 smallest match indices"; indices unique). Deterministic
// under arbitrary within-cell scatter order.
__global__ __launch_bounds__(256) void bq_grid(const float* __restrict__ pcs,
                                               const float4* __restrict__ sp4,
                                               const int* __restrict__ cellstart,
                                               unsigned short* __restrict__ idxu) {
    __shared__ int lists[4 * 128];
    const int tid = threadIdx.x;
    const int wid = tid >> 6, lane = tid & 63;
    const int b = blockIdx.x >> 10;                   // 1024 blocks per batch
    const int n = ((blockIdx.x & 1023) << 2) | wid;
    const int g = (b << 12) | n;
    const float* pb = pcs + (size_t)b * 3 * N_PTS;
    const float cxf = pb[n], cyf = pb[N_PTS + n], czf = pb[2 * N_PTS + n];
    const float csq = sq_exact(cxf, cyf, czf);
    const float4* sp = sp4 + ((size_t)b << 12);
    const int* cs = cellstart + b * 513;
    const float r2 = (float)(0.12 * 0.12);

    int cx = min(max((int)(cxf * 8.0f), 0), 7);
    int cy = min(max((int)(cyf * 8.0f), 0), 7);
    int cz = min(max((int)(czf * 8.0f), 0), 7);
    const int zlo = max(cz - 1, 0), zhi = min(cz + 1, 7);

    // 9-run table (wave-uniform scalars, static names only — rule #20)
#define RUN(k, dx, dy)                                                              \
    int rs##k = 0, ln##k = 0;                                                       \
    {                                                                               \
        int gx = cx + (dx), gy = cy + (dy);                                         \
        if (gx >= 0 && gx <= 7 && gy >= 0 && gy <= 7) {                             \
            int cb_ = (gx << 6) | (gy << 3);                                        \
            rs##k = cs[cb_ + zlo];                                                  \
            ln##k = cs[cb_ + zhi + 1] - rs##k;                                      \
        }                                                                           \
    }
    RUN(0, -1, -1) RUN(1, -1, 0) RUN(2, -1, 1)
    RUN(3,  0, -1) RUN(4,  0, 0) RUN(5,  0, 1)
    RUN(6,  1, -1) RUN(7,  1, 0) RUN(8,  1, 1)
#undef RUN
    const int c1 = ln0;
    const int c2 = c1 + ln1;
    const int c3 = c2 + ln2;
    const int c4 = c3 + ln3;
    const int c5 = c4 + ln4;
    const int c6 = c5 + ln5;
    const int c7 = c6 + ln6;
    const int c8 = c7 + ln7;
    const int TT = c8 + ln8;                          // total candidates (~216 avg)

    int f0 = BIGJ, f1 = BIGJ, f2 = BIGJ, f3 = BIGJ, f4 = BIGJ, f5 = BIGJ, f6 = BIGJ;
    int cnt = 0;
    int* lst = &lists[wid * 128];
    const unsigned long long ltm = (1ull << lane) - 1ull;

    for (int t0 = 0; t0 < TT; t0 += 64) {
        const int t = t0 + lane;
        const bool valid = t < TT;
        // stream position -> cell-sorted slot (static cndmask chain)
        int i = rs0 + t;
        i = (t >= c1) ? (rs1 + t - c1) : i;
        i = (t >= c2) ? (rs2 + t - c2) : i;
        i = (t >= c3) ? (rs3 + t - c3) : i;
        i = (t >= c4) ? (rs4 + t - c4) : i;
        i = (t >= c5) ? (rs5 + t - c5) : i;
        i = (t >= c6) ? (rs6 + t - c6) : i;
        i = (t >= c7) ? (rs7 + t - c7) : i;
        i = (t >= c8) ? (rs8 + t - c8) : i;
        const int ic = valid ? i : rs4;               // rs4 = center's own cell, always valid
        const float4 p = sp[ic];
        const int j = __builtin_bit_cast(int, p.w);
        const float psq = sq_exact(p.x, p.y, p.z);    // bit-identical to reference
        float dot = __fadd_rn(__fadd_rn(__fmul_rn(cxf, p.x), __fmul_rn(cyf, p.y)),
                              __fmul_rn(czf, p.z));
        float dd = __fsub_rn(__fadd_rn(csq, psq), __fmul_rn(2.0f, dot));
        const bool ok = valid && (dd <= r2) && (j != n);
        unsigned long long m = __ballot(ok);
        if (m) {
            int pos = cnt + __popcll(m & ltm);
            if (ok && pos < 128) lst[pos] = j;
            cnt += __popcll(m);
            const int oct = ((p.x >= cxf) ? 4 : 0) + ((p.y >= cyf) ? 2 : 0)
                          + ((p.z >= czf) ? 1 : 0);
            const int key = ok ? j : BIGJ;
            f0 = (oct == 0) ? min(f0, key) : f0;
            f1 = (oct == 1) ? min(f1, key) : f1;
            f2 = (oct == 2) ? min(f2, key) : f2;
            f3 = (oct == 3) ? min(f3, key) : f3;
            f4 = (oct == 4) ? min(f4, key) : f4;
            f5 = (oct == 5) ? min(f5, key) : f5;
            f6 = (oct == 6) ? min(f6, key) : f6;
        }
    }

    f0 = wmin(f0); f1 = wmin(f1); f2 = wmin(f2); f3 = wmin(f3);
    f4 = wmin(f4); f5 = wmin(f5); f6 = wmin(f6);

    if (cnt > 31) {
        // rank check against the (<=128) recorded matches; cnt>128 has ~0
        // probability at lambda~30 (same exposure as the sort it replaces)
        const int c2_ = min(cnt, 128);
        const int l0 = (lane < c2_) ? lst[lane] : BIGJ;
        const int l1 = (64 + lane < c2_) ? lst[64 + lane] : BIGJ;
#define RANKCHK(F)                                                                  \
        {                                                                           \
            int r_ = __popcll(__ballot(l0 < F)) + __popcll(__ballot(l1 < F));       \
            F = (r_ <= 30) ? F : BIGJ;                                              \
        }
        RANKCHK(f0) RANKCHK(f1) RANKCHK(f2) RANKCHK(f3)
        RANKCHK(f4) RANKCHK(f5) RANKCHK(f6)
#undef RANKCHK
    }

    int v = n;                                        // lane 0: center index
    if (lane == 1) v = f0;
    if (lane == 2) v = f1;
    if (lane == 3) v = f2;
    if (lane == 4) v = f3;
    if (lane == 5) v = f4;
    if (lane == 6) v = f5;
    if (lane == 7) v = f6;
    if (v > N_PTS) v = N_PTS;                         // BIGJ -> zeros row
    if (lane < 8) idxu[(size_t)g * 8 + lane] = (unsigned short)v;
}

// ---------------- kernel 5: transpose x [B,C,N] fp32 -> xbf [B][N+1][C] bf16 ----------
__global__ __launch_bounds__(256) void xpose_kernel(const float* __restrict__ x,
                                                    unsigned short* __restrict__ xbf) {
    __shared__ __attribute__((aligned(16))) unsigned short tile[64 * 132];
    const int tid = threadIdx.x;
    const int b = blockIdx.x / 65;
    const int j0 = (blockIdx.x % 65) * 64;
    if (j0 < N_PTS) {
        for (int c0 = 0; c0 < C_IN; c0 += 4) {
            int cc = c0 + (tid >> 6);
            int jj = tid & 63;
            float v = x[((size_t)b * C_IN + cc) * N_PTS + j0 + jj];
            tile[jj * 132 + cc] = f2bf(v);
        }
        __syncthreads();
        for (int i = 0; i < 8; ++i) {
            int idx = i * 256 + tid;          // 0..2047 -> 64 rows x 32 quads
            int row = idx >> 5, cq = idx & 31;
            uint2 v = *(const uint2*)&tile[row * 132 + cq * 4];
            *(uint2*)&xbf[((size_t)b * (N_PTS + 1) + j0 + row) * C_IN + cq * 4] = v;
        }
    } else {
        // zeros row j = 4096 (empty-octant gather target)
        for (int i = tid; i < C_IN; i += 256)
            xbf[((size_t)b * (N_PTS + 1) + N_PTS) * C_IN + i] = 0;
    }
}

// ---------------- kernel 6: gathered GEMM, bf16 MFMA 16x16x32 ----------------------
__global__ __launch_bounds__(256) void pconv_gemm(const unsigned short* __restrict__ xbf,
                                                  const unsigned short* __restrict__ wt,
                                                  const unsigned short* __restrict__ idxu,
                                                  const float* __restrict__ bias,
                                                  float* __restrict__ out) {
    __shared__ __attribute__((aligned(16))) unsigned short Plds[64 * 64];
    __shared__ __attribute__((aligned(16))) unsigned short Wlds[64 * 64];
    const int tid = threadIdx.x;
    const int tm = blockIdx.x >> 2, tn = blockIdx.x & 3;
    const int g0 = tm * 64;                  // global point-row base
    const int b  = g0 >> 12;
    const int nb = g0 & 4095;
    const int o0 = tn * 64;
    const int wid = tid >> 6, lane = tid & 63;
    const int wo = wid >> 1, wn = wid & 1;

    f32x4 acc[2][2] = {};

    for (int it = 0; it < 16; ++it) {
        const int k0 = it << 6;
        const int slot_id = k0 >> 7;         // which of the 8 gather slots
        const int cb = k0 & 127;             // channel base within slot
#pragma unroll
        for (int i = 0; i < 2; ++i) {
            const int Lb = i * 256 + wid * 64;          // wave-uniform 16B-slot base
            const int row = (Lb + lane) >> 3;           // tile row this lane feeds
            const int slog = (lane & 7) ^ (row & 7);    // pre-swizzled source slot
            // P: gathered point features
            int j = idxu[(size_t)(g0 + row) * 8 + slot_id];
            const unsigned short* psrc =
                xbf + ((size_t)b * (N_PTS + 1) + j) * C_IN + cb + slog * 8;
            gload_lds16(psrc, &Plds[Lb * 8]);
            // W: weight rows
            const unsigned short* wsrc =
                wt + (size_t)(o0 + row) * KDIM + k0 + slog * 8;
            gload_lds16(wsrc, &Wlds[Lb * 8]);
        }
        __syncthreads();
#pragma unroll
        for (int ks = 0; ks < 2; ++ks) {
            bf16x8 wf[2], pf[2];
#pragma unroll
            for (int f = 0; f < 2; ++f) {
                int orow = wo * 32 + f * 16 + (lane & 15);
                int slw = (ks * 4 + (lane >> 4)) ^ (orow & 7);
                wf[f] = *(const bf16x8*)&Wlds[orow * 64 + slw * 8];
                int nrow = wn * 32 + f * 16 + (lane & 15);
                int slp = (ks * 4 + (lane >> 4)) ^ (nrow & 7);
                pf[f] = *(const bf16x8*)&Plds[nrow * 64 + slp * 8];
            }
#pragma unroll
            for (int of = 0; of < 2; ++of)
#pragma unroll
                for (int nf = 0; nf < 2; ++nf)
                    acc[of][nf] = __builtin_amdgcn_mfma_f32_16x16x32_bf16(
                        wf[of], pf[nf], acc[of][nf], 0, 0, 0);
        }
        __syncthreads();
    }

#pragma unroll
    for (int of = 0; of < 2; ++of) {
        int o = o0 + wo * 32 + of * 16 + (lane >> 4) * 4;
#pragma unroll
        for (int nf = 0; nf < 2; ++nf) {
            int n = nb + wn * 32 + nf * 16 + (lane & 15);
#pragma unroll
            for (int r = 0; r < 4; ++r) {
                out[((size_t)b * C_OUT + o + r) * N_PTS + n] = acc[of][nf][r] + bias[o + r];
            }
        }
    }
}

extern "C" void kernel_launch(void* const* d_in, const int* in_sizes, int n_in,
                              void* d_out, int out_size, void* d_ws, size_t ws_size,
                              hipStream_t stream) {
    const float* x    = (const float*)d_in[0];
    const float* pcs  = (const float*)d_in[1];
    const float* w    = (const float*)d_in[2];
    const float* bias = (const float*)d_in[3];

    // ws layout (bytes) — total 5,260,304 < 5,506,048 proven-safe (rounds 1-3):
    char* base = (char*)d_ws;
    float4* sp4 = (float4*)base;                                    //       0 (262,144)
    unsigned short* xbf = (unsigned short*)(base + 262144);         // 4,195,328
    unsigned short* wt  = (unsigned short*)(base + 4457472);        //   524,288
    unsigned short* idxu = (unsigned short*)(base + 4981760);       //   262,144
    int* cellA     = (int*)(base + 5243904);                        //     8,192 (cnt->cursor)
    int* cellstart = (int*)(base + 5252096);                        //     8,208
    float* out = (float*)d_out;

    hipLaunchKernelGGL(prep_kernel,    dim3(1032),       dim3(256), 0, stream, w, wt, cellA);
    hipLaunchKernelGGL(count_kernel,   dim3(64),         dim3(256), 0, stream, pcs, cellA);
    hipLaunchKernelGGL(prefix_kernel,  dim3(BATCH),      dim3(512), 0, stream,
                       cellA, cellstart);
    hipLaunchKernelGGL(scatter_kernel, dim3(64),         dim3(256), 0, stream,
                       pcs, cellA, sp4);
    hipLaunchKernelGGL(bq_grid,        dim3(4096),       dim3(256), 0, stream,
                       pcs, sp4, cellstart, idxu);
    hipLaunchKernelGGL(xpose_kernel,   dim3(BATCH * 65), dim3(256), 0, stream, x, xbf);
    hipLaunchKernelGGL(pconv_gemm,     dim3(1024),       dim3(256), 0, stream,
                       xbf, wt, idxu, bias, out);
}

// Round 7
// 58.841 us; speedup vs baseline: 2.2199x; 1.0144x over previous
//
#include <hip/hip_runtime.h>
#include <stdint.h>

#define N_PTS 4096
#define BATCH 4
#define C_IN  128
#define C_OUT 256
#define KDIM  1024   // 8 active slots * 128 channels (octant-7 slot provably always zero)
#define NCELL 512    // 8x8x8 spatial grid, cell 0.125 >= radius 0.12
#define BIGJ  0x3fffffff

typedef __attribute__((ext_vector_type(8))) __bf16 bf16x8;
typedef __attribute__((ext_vector_type(4))) float  f32x4;

__device__ inline void gload_lds16(const void* g, void* l) {
    __builtin_amdgcn_global_load_lds(
        (__attribute__((address_space(1))) void*)(void*)(uintptr_t)g,
        (__attribute__((address_space(3))) void*)l, 16, 0, 0);
}

__device__ inline unsigned short f2bf(float v) {
    uint32_t u = __builtin_bit_cast(uint32_t, v);
    return (unsigned short)((u + 0x7fffu + ((u >> 16) & 1u)) >> 16);   // RTNE
}

// reference-exact sq = ((x*x + y*y) + z*z), no FMA contraction
__device__ inline float sq_exact(float x, float y, float z) {
    return __fadd_rn(__fadd_rn(__fmul_rn(x, x), __fmul_rn(y, y)), __fmul_rn(z, z));
}

__device__ inline int cell_of(float x, float y, float z) {
    int cx = (int)(x * 8.0f); cx = min(max(cx, 0), 7);
    int cy = (int)(y * 8.0f); cy = min(max(cy, 0), 7);
    int cz = (int)(z * 8.0f); cz = min(max(cz, 0), 7);
    return (cx << 6) | (cy << 3) | cz;
}

__device__ inline int wmin(int v) {
    for (int off = 32; off >= 1; off >>= 1) v = min(v, __shfl_xor(v, off, 64));
    return v;
}

// ---------------- kernel 0: prep — wt transpose + zero cell counters ----------------
__global__ __launch_bounds__(256) void prep_kernel(const float* __restrict__ w,
                                                   unsigned short* __restrict__ wt,
                                                   int* __restrict__ cellA) {
    const int bid = blockIdx.x;
    if (bid < 1024) {
        int gidx = bid * 256 + threadIdx.x;           // 0..262143
        int o = gidx >> 10, k = gidx & 1023;
        int slot = k >> 7, cch = k & 127;             // slot 0=center, slot s=octant s-1
        wt[gidx] = f2bf(w[(size_t)o * 1152 + cch * 9 + slot]);
    } else {
        int i = (bid - 1024) * 256 + threadIdx.x;     // 0..2047 == BATCH*NCELL
        cellA[i] = 0;
    }
}

// ---------------- kernel 1: count points per cell ----------------
__global__ __launch_bounds__(256) void count_kernel(const float* __restrict__ pcs,
                                                    int* __restrict__ cellA) {
    int i = blockIdx.x * 256 + threadIdx.x;           // 0..16383
    int b = i >> 12, n = i & 4095;
    const float* pb = pcs + (size_t)b * 3 * N_PTS;
    atomicAdd(&cellA[b * NCELL + cell_of(pb[n], pb[N_PTS + n], pb[2 * N_PTS + n])], 1);
}

// ---------------- kernel 2: exclusive prefix per batch (512 cells) ----------------
// Overwrites cellA in place with the exclusive prefix (becomes scatter cursor).
__global__ __launch_bounds__(512) void prefix_kernel(int* __restrict__ cellA,
                                                     int* __restrict__ cellstart) {
    __shared__ int sbuf[512];
    const int b = blockIdx.x, t = threadIdx.x;
    int v = cellA[b * NCELL + t];
    sbuf[t] = v;
    __syncthreads();
    for (int off = 1; off < 512; off <<= 1) {
        int tv = (t >= off) ? sbuf[t - off] : 0;
        __syncthreads();
        sbuf[t] += tv;
        __syncthreads();
    }
    int excl = sbuf[t] - v;
    cellstart[b * 513 + t] = excl;
    cellA[b * NCELL + t] = excl;
    if (t == 511) cellstart[b * 513 + 512] = sbuf[511];
}

// ---------------- kernel 3: scatter points into cell-sorted array ----------------
// sp4[slot] = (x, y, z, bitcast(original index j))
__global__ __launch_bounds__(256) void scatter_kernel(const float* __restrict__ pcs,
                                                      int* __restrict__ cellA,
                                                      float4* __restrict__ sp4) {
    int i = blockIdx.x * 256 + threadIdx.x;           // 0..16383
    int b = i >> 12, n = i & 4095;
    const float* pb = pcs + (size_t)b * 3 * N_PTS;
    float x = pb[n], y = pb[N_PTS + n], z = pb[2 * N_PTS + n];
    int slot = atomicAdd(&cellA[b * NCELL + cell_of(x, y, z)], 1);
    float4 v = make_float4(x, y, z, __builtin_bit_cast(float, n));
    sp4[(b << 12) + slot] = v;
}

// ---------------- kernel 4: grid ball query — one wave per center ----------------
// Merged 27-cell candidate stream (wave-uniform run table + cndmask chain),
// 1-deep software pipeline: next chunk's address+load issue before current
// chunk's ballot/min work (load is cnt-independent -> latency hidden).
// Octant firsts are order-free mins; 31-cap via rank check (deterministic).
__global__ __launch_bounds__(256) void bq_grid(const float* __restrict__ pcs,
                                               const float4* __restrict__ sp4,
                                               const int* __restrict__ cellstart,
                                               unsigned short* __restrict__ idxu) {
    __shared__ int lists[4 * 128];
    const int tid = threadIdx.x;
    const int wid = tid >> 6, lane = tid & 63;
    const int b = blockIdx.x >> 10;                   // 1024 blocks per batch
    const int n = ((blockIdx.x & 1023) << 2) | wid;
    const int g = (b << 12) | n;
    const float* pb = pcs + (size_t)b * 3 * N_PTS;
    const float cxf = pb[n], cyf = pb[N_PTS + n], czf = pb[2 * N_PTS + n];
    const float csq = sq_exact(cxf, cyf, czf);
    const float4* sp = sp4 + ((size_t)b << 12);
    const int* cs = cellstart + b * 513;
    const float r2 = (float)(0.12 * 0.12);

    int cx = min(max((int)(cxf * 8.0f), 0), 7);
    int cy = min(max((int)(cyf * 8.0f), 0), 7);
    int cz = min(max((int)(czf * 8.0f), 0), 7);
    const int zlo = max(cz - 1, 0), zhi = min(cz + 1, 7);

    // 9-run table (wave-uniform scalars, static names only — rule #20)
#define RUN(k, dx, dy)                                                              \
    int rs##k = 0, ln##k = 0;                                                       \
    {                                                                               \
        int gx = cx + (dx), gy = cy + (dy);                                         \
        if (gx >= 0 && gx <= 7 && gy >= 0 && gy <= 7) {                             \
            int cb_ = (gx << 6) | (gy << 3);                                        \
            rs##k = cs[cb_ + zlo];                                                  \
            ln##k = cs[cb_ + zhi + 1] - rs##k;                                      \
        }                                                                           \
    }
    RUN(0, -1, -1) RUN(1, -1, 0) RUN(2, -1, 1)
    RUN(3,  0, -1) RUN(4,  0, 0) RUN(5,  0, 1)
    RUN(6,  1, -1) RUN(7,  1, 0) RUN(8,  1, 1)
#undef RUN
    const int c1 = ln0;
    const int c2 = c1 + ln1;
    const int c3 = c2 + ln2;
    const int c4 = c3 + ln3;
    const int c5 = c4 + ln4;
    const int c6 = c5 + ln5;
    const int c7 = c6 + ln6;
    const int c8 = c7 + ln7;
    const int TT = c8 + ln8;                          // total candidates (~216 avg)

    // stream position -> cell-sorted slot (static cndmask chain, clamped safe)
#define CAND_IDX(T, OUTI)                                                           \
    {                                                                               \
        const int t_ = (T);                                                         \
        int i_ = rs0 + t_;                                                          \
        i_ = (t_ >= c1) ? (rs1 + t_ - c1) : i_;                                     \
        i_ = (t_ >= c2) ? (rs2 + t_ - c2) : i_;                                     \
        i_ = (t_ >= c3) ? (rs3 + t_ - c3) : i_;                                     \
        i_ = (t_ >= c4) ? (rs4 + t_ - c4) : i_;                                     \
        i_ = (t_ >= c5) ? (rs5 + t_ - c5) : i_;                                     \
        i_ = (t_ >= c6) ? (rs6 + t_ - c6) : i_;                                     \
        i_ = (t_ >= c7) ? (rs7 + t_ - c7) : i_;                                     \
        i_ = (t_ >= c8) ? (rs8 + t_ - c8) : i_;                                     \
        OUTI = (t_ < TT) ? i_ : rs4;   /* rs4 = center's own cell, always valid */  \
    }

    int f0 = BIGJ, f1 = BIGJ, f2 = BIGJ, f3 = BIGJ, f4 = BIGJ, f5 = BIGJ, f6 = BIGJ;
    int cnt = 0;
    int* lst = &lists[wid * 128];
    const unsigned long long ltm = (1ull << lane) - 1ull;

    int ic0;
    CAND_IDX(lane, ic0)
    float4 p_cur = sp[ic0];                           // prologue load (TT >= 1 always)

    for (int t0 = 0; t0 < TT; t0 += 64) {
        int icn;
        CAND_IDX(t0 + 64 + lane, icn)
        const float4 p_nxt = sp[icn];                 // prefetch next chunk

        const bool valid = (t0 + lane) < TT;
        const float4 p = p_cur;
        const int j = __builtin_bit_cast(int, p.w);
        const float psq = sq_exact(p.x, p.y, p.z);    // bit-identical to reference
        float dot = __fadd_rn(__fadd_rn(__fmul_rn(cxf, p.x), __fmul_rn(cyf, p.y)),
                              __fmul_rn(czf, p.z));
        float dd = __fsub_rn(__fadd_rn(csq, psq), __fmul_rn(2.0f, dot));
        const bool ok = valid && (dd <= r2) && (j != n);
        unsigned long long m = __ballot(ok);
        if (m) {
            int pos = cnt + __popcll(m & ltm);
            if (ok && pos < 128) lst[pos] = j;
            cnt += __popcll(m);
            const int oct = ((p.x >= cxf) ? 4 : 0) + ((p.y >= cyf) ? 2 : 0)
                          + ((p.z >= czf) ? 1 : 0);
            const int key = ok ? j : BIGJ;
            f0 = (oct == 0) ? min(f0, key) : f0;
            f1 = (oct == 1) ? min(f1, key) : f1;
            f2 = (oct == 2) ? min(f2, key) : f2;
            f3 = (oct == 3) ? min(f3, key) : f3;
            f4 = (oct == 4) ? min(f4, key) : f4;
            f5 = (oct == 5) ? min(f5, key) : f5;
            f6 = (oct == 6) ? min(f6, key) : f6;
        }
        p_cur = p_nxt;
    }
#undef CAND_IDX

    f0 = wmin(f0); f1 = wmin(f1); f2 = wmin(f2); f3 = wmin(f3);
    f4 = wmin(f4); f5 = wmin(f5); f6 = wmin(f6);

    if (cnt > 31) {
        // rank check against the (<=128) recorded matches; cnt>128 has ~0
        // probability at lambda~30 (same exposure as the sort it replaced)
        const int c2_ = min(cnt, 128);
        const int l0 = (lane < c2_) ? lst[lane] : BIGJ;
        const int l1 = (64 + lane < c2_) ? lst[64 + lane] : BIGJ;
#define RANKCHK(F)                                                                  \
        {                                                                           \
            int r_ = __popcll(__ballot(l0 < F)) + __popcll(__ballot(l1 < F));       \
            F = (r_ <= 30) ? F : BIGJ;                                              \
        }
        RANKCHK(f0) RANKCHK(f1) RANKCHK(f2) RANKCHK(f3)
        RANKCHK(f4) RANKCHK(f5) RANKCHK(f6)
#undef RANKCHK
    }

    int v = n;                                        // lane 0: center index
    if (lane == 1) v = f0;
    if (lane == 2) v = f1;
    if (lane == 3) v = f2;
    if (lane == 4) v = f3;
    if (lane == 5) v = f4;
    if (lane == 6) v = f5;
    if (lane == 7) v = f6;
    if (v > N_PTS) v = N_PTS;                         // BIGJ -> zeros row
    if (lane < 8) idxu[(size_t)g * 8 + lane] = (unsigned short)v;
}

// ---------------- kernel 5: transpose x [B,C,N] fp32 -> xbf [B][N+1][C] bf16 ----------
__global__ __launch_bounds__(256) void xpose_kernel(const float* __restrict__ x,
                                                    unsigned short* __restrict__ xbf) {
    __shared__ __attribute__((aligned(16))) unsigned short tile[64 * 132];
    const int tid = threadIdx.x;
    const int b = blockIdx.x / 65;
    const int j0 = (blockIdx.x % 65) * 64;
    if (j0 < N_PTS) {
        for (int c0 = 0; c0 < C_IN; c0 += 4) {
            int cc = c0 + (tid >> 6);
            int jj = tid & 63;
            float v = x[((size_t)b * C_IN + cc) * N_PTS + j0 + jj];
            tile[jj * 132 + cc] = f2bf(v);
        }
        __syncthreads();
        for (int i = 0; i < 8; ++i) {
            int idx = i * 256 + tid;          // 0..2047 -> 64 rows x 32 quads
            int row = idx >> 5, cq = idx & 31;
            uint2 v = *(const uint2*)&tile[row * 132 + cq * 4];
            *(uint2*)&xbf[((size_t)b * (N_PTS + 1) + j0 + row) * C_IN + cq * 4] = v;
        }
    } else {
        // zeros row j = 4096 (empty-octant gather target)
        for (int i = tid; i < C_IN; i += 256)
            xbf[((size_t)b * (N_PTS + 1) + N_PTS) * C_IN + i] = 0;
    }
}

// ---------------- kernel 6: gathered GEMM, 128x128 tile, bf16 MFMA 16x16x32 ---------
// 8 waves (512 thr), BK=64, 1 block/CU (grid 256). Halves L2 staging traffic vs
// 64^2 and 4x the MFMA per barrier pair. Same swizzle algebra as the proven 64^2:
// linear LDS dest + pre-swizzled global source slot (slog), swizzled ds_read.
__global__ __launch_bounds__(512) void pconv_gemm(const unsigned short* __restrict__ xbf,
                                                  const unsigned short* __restrict__ wt,
                                                  const unsigned short* __restrict__ idxu,
                                                  const float* __restrict__ bias,
                                                  float* __restrict__ out) {
    __shared__ __attribute__((aligned(16))) unsigned short Plds[128 * 64];
    __shared__ __attribute__((aligned(16))) unsigned short Wlds[128 * 64];
    const int tid = threadIdx.x;
    const int tm = blockIdx.x >> 1, tn = blockIdx.x & 1;  // 128 M-tiles x 2 N-tiles
    const int g0 = tm * 128;                 // global point-row base
    const int b  = g0 >> 12;
    const int nb = g0 & 4095;
    const int o0 = tn * 128;
    const int wid = tid >> 6, lane = tid & 63;
    const int wo = wid >> 1, wn = wid & 1;   // wave -> 32 o-rows x 64 n-cols

    f32x4 acc[2][4] = {};

    for (int it = 0; it < 16; ++it) {
        const int k0 = it << 6;
        const int slot_id = it >> 1;         // gather slot (128 K per slot)
        const int cb = (it & 1) << 6;        // channel base within slot
#pragma unroll
        for (int i = 0; i < 2; ++i) {
            const int Lb = i * 512 + wid * 64;          // wave-uniform 16B-slot base
            const int row = (Lb + lane) >> 3;           // tile row this lane feeds
            const int slog = (lane & 7) ^ (row & 7);    // pre-swizzled source slot
            // P: gathered point features
            int j = idxu[(size_t)(g0 + row) * 8 + slot_id];
            gload_lds16(xbf + ((size_t)b * (N_PTS + 1) + j) * C_IN + cb + slog * 8,
                        &Plds[Lb * 8]);
            // W: weight rows
            gload_lds16(wt + (size_t)(o0 + row) * KDIM + k0 + slog * 8,
                        &Wlds[Lb * 8]);
        }
        __syncthreads();
#pragma unroll
        for (int ks = 0; ks < 2; ++ks) {
            bf16x8 wf[2], pf[4];
#pragma unroll
            for (int f = 0; f < 2; ++f) {
                int orow = wo * 32 + f * 16 + (lane & 15);
                int slw = (ks * 4 + (lane >> 4)) ^ (orow & 7);
                wf[f] = *(const bf16x8*)&Wlds[orow * 64 + slw * 8];
            }
#pragma unroll
            for (int q = 0; q < 4; ++q) {
                int nrow = wn * 64 + q * 16 + (lane & 15);
                int slp = (ks * 4 + (lane >> 4)) ^ (nrow & 7);
                pf[q] = *(const bf16x8*)&Plds[nrow * 64 + slp * 8];
            }
#pragma unroll
            for (int f = 0; f < 2; ++f)
#pragma unroll
                for (int q = 0; q < 4; ++q)
                    acc[f][q] = __builtin_amdgcn_mfma_f32_16x16x32_bf16(
                        wf[f], pf[q], acc[f][q], 0, 0, 0);
        }
        __syncthreads();
    }

#pragma unroll
    for (int f = 0; f < 2; ++f) {
        int o = o0 + wo * 32 + f * 16 + (lane >> 4) * 4;
#pragma unroll
        for (int q = 0; q < 4; ++q) {
            int n = nb + wn * 64 + q * 16 + (lane & 15);
#pragma unroll
            for (int r = 0; r < 4; ++r) {
                out[((size_t)b * C_OUT + o + r) * N_PTS + n] = acc[f][q][r] + bias[o + r];
            }
        }
    }
}

extern "C" void kernel_launch(void* const* d_in, const int* in_sizes, int n_in,
                              void* d_out, int out_size, void* d_ws, size_t ws_size,
                              hipStream_t stream) {
    const float* x    = (const float*)d_in[0];
    const float* pcs  = (const float*)d_in[1];
    const float* w    = (const float*)d_in[2];
    const float* bias = (const float*)d_in[3];

    // ws layout (bytes) — total 5,260,304 < 5,506,048 proven-safe (rounds 1-3):
    char* base = (char*)d_ws;
    float4* sp4 = (float4*)base;                                    //       0 (262,144)
    unsigned short* xbf = (unsigned short*)(base + 262144);         // 4,195,328
    unsigned short* wt  = (unsigned short*)(base + 4457472);        //   524,288
    unsigned short* idxu = (unsigned short*)(base + 4981760);       //   262,144
    int* cellA     = (int*)(base + 5243904);                        //     8,192 (cnt->cursor)
    int* cellstart = (int*)(base + 5252096);                        //     8,208
    float* out = (float*)d_out;

    hipLaunchKernelGGL(prep_kernel,    dim3(1032),       dim3(256), 0, stream, w, wt, cellA);
    hipLaunchKernelGGL(count_kernel,   dim3(64),         dim3(256), 0, stream, pcs, cellA);
    hipLaunchKernelGGL(prefix_kernel,  dim3(BATCH),      dim3(512), 0, stream,
                       cellA, cellstart);
    hipLaunchKernelGGL(scatter_kernel, dim3(64),         dim3(256), 0, stream,
                       pcs, cellA, sp4);
    hipLaunchKernelGGL(bq_grid,        dim3(4096),       dim3(256), 0, stream,
                       pcs, sp4, cellstart, idxu);
    hipLaunchKernelGGL(xpose_kernel,   dim3(BATCH * 65), dim3(256), 0, stream, x, xbf);
    hipLaunchKernelGGL(pconv_gemm,     dim3(256),        dim3(512), 0, stream,
                       xbf, wt, idxu, bias, out);
}

// Round 8
// 51.730 us; speedup vs baseline: 2.5251x; 1.1375x over previous
//
#include <hip/hip_runtime.h>
#include <stdint.h>

#define N_PTS 4096
#define BATCH 4
#define C_IN  128
#define C_OUT 256
#define KDIM  1024   // 8 active slots * 128 channels (octant-7 slot provably always zero)
#define NCELL 512    // 8x8x8 spatial grid, cell 0.125 >= radius 0.12
#define BIGJ  0x3fffffff

typedef __attribute__((ext_vector_type(8))) __bf16 bf16x8;
typedef __attribute__((ext_vector_type(4))) float  f32x4;

__device__ inline void gload_lds16(const void* g, void* l) {
    __builtin_amdgcn_global_load_lds(
        (__attribute__((address_space(1))) void*)(void*)(uintptr_t)g,
        (__attribute__((address_space(3))) void*)l, 16, 0, 0);
}

__device__ inline unsigned short f2bf(float v) {
    uint32_t u = __builtin_bit_cast(uint32_t, v);
    return (unsigned short)((u + 0x7fffu + ((u >> 16) & 1u)) >> 16);   // RTNE
}

// reference-exact sq = ((x*x + y*y) + z*z), no FMA contraction
__device__ inline float sq_exact(float x, float y, float z) {
    return __fadd_rn(__fadd_rn(__fmul_rn(x, x), __fmul_rn(y, y)), __fmul_rn(z, z));
}

__device__ inline int cell_of(float x, float y, float z) {
    int cx = (int)(x * 8.0f); cx = min(max(cx, 0), 7);
    int cy = (int)(y * 8.0f); cy = min(max(cy, 0), 7);
    int cz = (int)(z * 8.0f); cz = min(max(cz, 0), 7);
    return (cx << 6) | (cy << 3) | cz;
}

__device__ inline int wmin(int v) {
    for (int off = 32; off >= 1; off >>= 1) v = min(v, __shfl_xor(v, off, 64));
    return v;
}

// ---------------- kernel 1: fused prep ----------------
// bid [0,1024):      wt transpose [256,128,1,9] fp32 -> wt[o][kappa] bf16
// bid [1024,1284):   x transpose [B,C,N] fp32 -> xbf [B][N+1][C] bf16 (+zeros row)
// bid [1284,1288):   per-batch grid build: count -> prefix -> scatter, all in LDS
__global__ __launch_bounds__(256) void fused_prep(const float* __restrict__ w,
                                                  unsigned short* __restrict__ wt,
                                                  const float* __restrict__ x,
                                                  unsigned short* __restrict__ xbf,
                                                  const float* __restrict__ pcs,
                                                  float4* __restrict__ sp4,
                                                  int* __restrict__ cellstart) {
    const int bid = blockIdx.x;
    const int tid = threadIdx.x;

    if (bid < 1024) {
        // ---- weight transpose ----
        int gidx = bid * 256 + tid;                   // 0..262143
        int o = gidx >> 10, k = gidx & 1023;
        int slot = k >> 7, cch = k & 127;             // slot 0=center, slot s=octant s-1
        wt[gidx] = f2bf(w[(size_t)o * 1152 + cch * 9 + slot]);
    } else if (bid < 1284) {
        // ---- feature transpose ----
        __shared__ __attribute__((aligned(16))) unsigned short tile[64 * 132];
        const int bb = bid - 1024;
        const int b = bb / 65;
        const int j0 = (bb % 65) * 64;
        if (j0 < N_PTS) {
            for (int c0 = 0; c0 < C_IN; c0 += 4) {
                int cc = c0 + (tid >> 6);
                int jj = tid & 63;
                float v = x[((size_t)b * C_IN + cc) * N_PTS + j0 + jj];
                tile[jj * 132 + cc] = f2bf(v);
            }
            __syncthreads();
            for (int i = 0; i < 8; ++i) {
                int idx = i * 256 + tid;      // 0..2047 -> 64 rows x 32 quads
                int row = idx >> 5, cq = idx & 31;
                uint2 v = *(const uint2*)&tile[row * 132 + cq * 4];
                *(uint2*)&xbf[((size_t)b * (N_PTS + 1) + j0 + row) * C_IN + cq * 4] = v;
            }
        } else {
            // zeros row j = 4096 (empty-octant gather target)
            for (int i = tid; i < C_IN; i += 256)
                xbf[((size_t)b * (N_PTS + 1) + N_PTS) * C_IN + i] = 0;
        }
    } else {
        // ---- grid build for batch b: count -> prefix -> scatter (LDS) ----
        __shared__ int scnt[NCELL];                   // counts -> cursors
        __shared__ int pairs[256];
        const int b = bid - 1284;
        const float* pb = pcs + (size_t)b * 3 * N_PTS;
        for (int i = tid; i < NCELL; i += 256) scnt[i] = 0;
        __syncthreads();
        // count (16 points per thread)
        for (int k = 0; k < 16; ++k) {
            int n = k * 256 + tid;
            atomicAdd(&scnt[cell_of(pb[n], pb[N_PTS + n], pb[2 * N_PTS + n])], 1);
        }
        __syncthreads();
        // exclusive prefix over 512 cells (2 cells/thread + Hillis-Steele on pair sums)
        const int a0 = scnt[2 * tid], a1 = scnt[2 * tid + 1];
        pairs[tid] = a0 + a1;
        __syncthreads();
        for (int off = 1; off < 256; off <<= 1) {
            int v = (tid >= off) ? pairs[tid - off] : 0;
            __syncthreads();
            pairs[tid] += v;
            __syncthreads();
        }
        const int epair = pairs[tid] - (a0 + a1);     // exclusive pair prefix
        cellstart[b * 513 + 2 * tid]     = epair;
        cellstart[b * 513 + 2 * tid + 1] = epair + a0;
        scnt[2 * tid]     = epair;                    // cursors
        scnt[2 * tid + 1] = epair + a0;
        if (tid == 255) cellstart[b * 513 + 512] = epair + a0 + a1;
        __syncthreads();
        // scatter: sp4[slot] = (x, y, z, bitcast(original index n))
        for (int k = 0; k < 16; ++k) {
            int n = k * 256 + tid;
            float px = pb[n], py = pb[N_PTS + n], pz = pb[2 * N_PTS + n];
            int slot = atomicAdd(&scnt[cell_of(px, py, pz)], 1);
            sp4[(b << 12) + slot] = make_float4(px, py, pz, __builtin_bit_cast(float, n));
        }
    }
}

// ---------------- kernel 2: grid ball query — one wave per center ----------------
// Merged 27-cell candidate stream (wave-uniform run table + cndmask chain),
// 1-deep software pipeline: next chunk's address+load issue before current
// chunk's ballot/min work. Octant firsts are order-free mins; 31-cap via rank
// check (deterministic under arbitrary within-cell scatter order).
__global__ __launch_bounds__(256) void bq_grid(const float* __restrict__ pcs,
                                               const float4* __restrict__ sp4,
                                               const int* __restrict__ cellstart,
                                               unsigned short* __restrict__ idxu) {
    __shared__ int lists[4 * 128];
    const int tid = threadIdx.x;
    const int wid = tid >> 6, lane = tid & 63;
    const int b = blockIdx.x >> 10;                   // 1024 blocks per batch
    const int n = ((blockIdx.x & 1023) << 2) | wid;
    const int g = (b << 12) | n;
    const float* pb = pcs + (size_t)b * 3 * N_PTS;
    const float cxf = pb[n], cyf = pb[N_PTS + n], czf = pb[2 * N_PTS + n];
    const float csq = sq_exact(cxf, cyf, czf);
    const float4* sp = sp4 + ((size_t)b << 12);
    const int* cs = cellstart + b * 513;
    const float r2 = (float)(0.12 * 0.12);

    int cx = min(max((int)(cxf * 8.0f), 0), 7);
    int cy = min(max((int)(cyf * 8.0f), 0), 7);
    int cz = min(max((int)(czf * 8.0f), 0), 7);
    const int zlo = max(cz - 1, 0), zhi = min(cz + 1, 7);

    // 9-run table (wave-uniform scalars, static names only — rule #20)
#define RUN(k, dx, dy)                                                              \
    int rs##k = 0, ln##k = 0;                                                       \
    {                                                                               \
        int gx = cx + (dx), gy = cy + (dy);                                         \
        if (gx >= 0 && gx <= 7 && gy >= 0 && gy <= 7) {                             \
            int cb_ = (gx << 6) | (gy << 3);                                        \
            rs##k = cs[cb_ + zlo];                                                  \
            ln##k = cs[cb_ + zhi + 1] - rs##k;                                      \
        }                                                                           \
    }
    RUN(0, -1, -1) RUN(1, -1, 0) RUN(2, -1, 1)
    RUN(3,  0, -1) RUN(4,  0, 0) RUN(5,  0, 1)
    RUN(6,  1, -1) RUN(7,  1, 0) RUN(8,  1, 1)
#undef RUN
    const int c1 = ln0;
    const int c2 = c1 + ln1;
    const int c3 = c2 + ln2;
    const int c4 = c3 + ln3;
    const int c5 = c4 + ln4;
    const int c6 = c5 + ln5;
    const int c7 = c6 + ln6;
    const int c8 = c7 + ln7;
    const int TT = c8 + ln8;                          // total candidates (~216 avg)

    // stream position -> cell-sorted slot (static cndmask chain, clamped safe)
#define CAND_IDX(T, OUTI)                                                           \
    {                                                                               \
        const int t_ = (T);                                                         \
        int i_ = rs0 + t_;                                                          \
        i_ = (t_ >= c1) ? (rs1 + t_ - c1) : i_;                                     \
        i_ = (t_ >= c2) ? (rs2 + t_ - c2) : i_;                                     \
        i_ = (t_ >= c3) ? (rs3 + t_ - c3) : i_;                                     \
        i_ = (t_ >= c4) ? (rs4 + t_ - c4) : i_;                                     \
        i_ = (t_ >= c5) ? (rs5 + t_ - c5) : i_;                                     \
        i_ = (t_ >= c6) ? (rs6 + t_ - c6) : i_;                                     \
        i_ = (t_ >= c7) ? (rs7 + t_ - c7) : i_;                                     \
        i_ = (t_ >= c8) ? (rs8 + t_ - c8) : i_;                                     \
        OUTI = (t_ < TT) ? i_ : rs4;   /* rs4 = center's own cell, always valid */  \
    }

    int f0 = BIGJ, f1 = BIGJ, f2 = BIGJ, f3 = BIGJ, f4 = BIGJ, f5 = BIGJ, f6 = BIGJ;
    int cnt = 0;
    int* lst = &lists[wid * 128];
    const unsigned long long ltm = (1ull << lane) - 1ull;

    int ic0;
    CAND_IDX(lane, ic0)
    float4 p_cur = sp[ic0];                           // prologue load (TT >= 1 always)

    for (int t0 = 0; t0 < TT; t0 += 64) {
        int icn;
        CAND_IDX(t0 + 64 + lane, icn)
        const float4 p_nxt = sp[icn];                 // prefetch next chunk

        const bool valid = (t0 + lane) < TT;
        const float4 p = p_cur;
        const int j = __builtin_bit_cast(int, p.w);
        const float psq = sq_exact(p.x, p.y, p.z);    // bit-identical to reference
        float dot = __fadd_rn(__fadd_rn(__fmul_rn(cxf, p.x), __fmul_rn(cyf, p.y)),
                              __fmul_rn(czf, p.z));
        float dd = __fsub_rn(__fadd_rn(csq, psq), __fmul_rn(2.0f, dot));
        const bool ok = valid && (dd <= r2) && (j != n);
        unsigned long long m = __ballot(ok);
        if (m) {
            int pos = cnt + __popcll(m & ltm);
            if (ok && pos < 128) lst[pos] = j;
            cnt += __popcll(m);
            const int oct = ((p.x >= cxf) ? 4 : 0) + ((p.y >= cyf) ? 2 : 0)
                          + ((p.z >= czf) ? 1 : 0);
            const int key = ok ? j : BIGJ;
            f0 = (oct == 0) ? min(f0, key) : f0;
            f1 = (oct == 1) ? min(f1, key) : f1;
            f2 = (oct == 2) ? min(f2, key) : f2;
            f3 = (oct == 3) ? min(f3, key) : f3;
            f4 = (oct == 4) ? min(f4, key) : f4;
            f5 = (oct == 5) ? min(f5, key) : f5;
            f6 = (oct == 6) ? min(f6, key) : f6;
        }
        p_cur = p_nxt;
    }
#undef CAND_IDX

    f0 = wmin(f0); f1 = wmin(f1); f2 = wmin(f2); f3 = wmin(f3);
    f4 = wmin(f4); f5 = wmin(f5); f6 = wmin(f6);

    if (cnt > 31) {
        // rank check against the (<=128) recorded matches; cnt>128 has ~0
        // probability at lambda~30 (same exposure as the sort it replaced)
        const int c2_ = min(cnt, 128);
        const int l0 = (lane < c2_) ? lst[lane] : BIGJ;
        const int l1 = (64 + lane < c2_) ? lst[64 + lane] : BIGJ;
#define RANKCHK(F)                                                                  \
        {                                                                           \
            int r_ = __popcll(__ballot(l0 < F)) + __popcll(__ballot(l1 < F));       \
            F = (r_ <= 30) ? F : BIGJ;                                              \
        }
        RANKCHK(f0) RANKCHK(f1) RANKCHK(f2) RANKCHK(f3)
        RANKCHK(f4) RANKCHK(f5) RANKCHK(f6)
#undef RANKCHK
    }

    int v = n;                                        // lane 0: center index
    if (lane == 1) v = f0;
    if (lane == 2) v = f1;
    if (lane == 3) v = f2;
    if (lane == 4) v = f3;
    if (lane == 5) v = f4;
    if (lane == 6) v = f5;
    if (lane == 7) v = f6;
    if (v > N_PTS) v = N_PTS;                         // BIGJ -> zeros row
    if (lane < 8) idxu[(size_t)g * 8 + lane] = (unsigned short)v;
}

// ---------------- kernel 3: gathered GEMM, 128x128 tile, bf16 MFMA 16x16x32 ---------
// 8 waves (512 thr), BK=64, 1 block/CU (grid 256). Linear LDS dest + pre-swizzled
// global source slot (slog), swizzled ds_read.
__global__ __launch_bounds__(512) void pconv_gemm(const unsigned short* __restrict__ xbf,
                                                  const unsigned short* __restrict__ wt,
                                                  const unsigned short* __restrict__ idxu,
                                                  const float* __restrict__ bias,
                                                  float* __restrict__ out) {
    __shared__ __attribute__((aligned(16))) unsigned short Plds[128 * 64];
    __shared__ __attribute__((aligned(16))) unsigned short Wlds[128 * 64];
    const int tid = threadIdx.x;
    const int tm = blockIdx.x >> 1, tn = blockIdx.x & 1;  // 128 M-tiles x 2 N-tiles
    const int g0 = tm * 128;                 // global point-row base
    const int b  = g0 >> 12;
    const int nb = g0 & 4095;
    const int o0 = tn * 128;
    const int wid = tid >> 6, lane = tid & 63;
    const int wo = wid >> 1, wn = wid & 1;   // wave -> 32 o-rows x 64 n-cols

    f32x4 acc[2][4] = {};

    for (int it = 0; it < 16; ++it) {
        const int k0 = it << 6;
        const int slot_id = it >> 1;         // gather slot (128 K per slot)
        const int cb = (it & 1) << 6;        // channel base within slot
#pragma unroll
        for (int i = 0; i < 2; ++i) {
            const int Lb = i * 512 + wid * 64;          // wave-uniform 16B-slot base
            const int row = (Lb + lane) >> 3;           // tile row this lane feeds
            const int slog = (lane & 7) ^ (row & 7);    // pre-swizzled source slot
            // P: gathered point features
            int j = idxu[(size_t)(g0 + row) * 8 + slot_id];
            gload_lds16(xbf + ((size_t)b * (N_PTS + 1) + j) * C_IN + cb + slog * 8,
                        &Plds[Lb * 8]);
            // W: weight rows
            gload_lds16(wt + (size_t)(o0 + row) * KDIM + k0 + slog * 8,
                        &Wlds[Lb * 8]);
        }
        __syncthreads();
#pragma unroll
        for (int ks = 0; ks < 2; ++ks) {
            bf16x8 wf[2], pf[4];
#pragma unroll
            for (int f = 0; f < 2; ++f) {
                int orow = wo * 32 + f * 16 + (lane & 15);
                int slw = (ks * 4 + (lane >> 4)) ^ (orow & 7);
                wf[f] = *(const bf16x8*)&Wlds[orow * 64 + slw * 8];
            }
#pragma unroll
            for (int q = 0; q < 4; ++q) {
                int nrow = wn * 64 + q * 16 + (lane & 15);
                int slp = (ks * 4 + (lane >> 4)) ^ (nrow & 7);
                pf[q] = *(const bf16x8*)&Plds[nrow * 64 + slp * 8];
            }
#pragma unroll
            for (int f = 0; f < 2; ++f)
#pragma unroll
                for (int q = 0; q < 4; ++q)
                    acc[f][q] = __builtin_amdgcn_mfma_f32_16x16x32_bf16(
                        wf[f], pf[q], acc[f][q], 0, 0, 0);
        }
        __syncthreads();
    }

#pragma unroll
    for (int f = 0; f < 2; ++f) {
        int o = o0 + wo * 32 + f * 16 + (lane >> 4) * 4;
#pragma unroll
        for (int q = 0; q < 4; ++q) {
            int n = nb + wn * 64 + q * 16 + (lane & 15);
#pragma unroll
            for (int r = 0; r < 4; ++r) {
                out[((size_t)b * C_OUT + o + r) * N_PTS + n] = acc[f][q][r] + bias[o + r];
            }
        }
    }
}

extern "C" void kernel_launch(void* const* d_in, const int* in_sizes, int n_in,
                              void* d_out, int out_size, void* d_ws, size_t ws_size,
                              hipStream_t stream) {
    const float* x    = (const float*)d_in[0];
    const float* pcs  = (const float*)d_in[1];
    const float* w    = (const float*)d_in[2];
    const float* bias = (const float*)d_in[3];

    // ws layout (bytes) — total 5,252,112 < 5,506,048 proven-safe (rounds 1-3):
    char* base = (char*)d_ws;
    float4* sp4 = (float4*)base;                                    //       0 (262,144)
    unsigned short* xbf = (unsigned short*)(base + 262144);         // 4,195,328
    unsigned short* wt  = (unsigned short*)(base + 4457472);        //   524,288
    unsigned short* idxu = (unsigned short*)(base + 4981760);       //   262,144
    int* cellstart = (int*)(base + 5243904);                        //     8,208
    float* out = (float*)d_out;

    hipLaunchKernelGGL(fused_prep, dim3(1288), dim3(256), 0, stream,
                       w, wt, x, xbf, pcs, sp4, cellstart);
    hipLaunchKernelGGL(bq_grid,    dim3(4096), dim3(256), 0, stream,
                       pcs, sp4, cellstart, idxu);
    hipLaunchKernelGGL(pconv_gemm, dim3(256),  dim3(512), 0, stream,
                       xbf, wt, idxu, bias, out);
}

// Round 9
// 50.686 us; speedup vs baseline: 2.5770x; 1.0206x over previous
//
#include <hip/hip_runtime.h>
#include <stdint.h>

#define N_PTS 4096
#define BATCH 4
#define C_IN  128
#define C_OUT 256
#define KDIM  1024   // 8 active slots * 128 channels (octant-7 slot provably always zero)
#define NCELL 512    // 8x8x8 spatial grid, cell 0.125 >= radius 0.12
#define BIGJ  0x3fffffff

typedef __attribute__((ext_vector_type(8))) __bf16 bf16x8;
typedef __attribute__((ext_vector_type(4))) float  f32x4;

__device__ inline void gload_lds16(const void* g, void* l) {
    __builtin_amdgcn_global_load_lds(
        (__attribute__((address_space(1))) void*)(void*)(uintptr_t)g,
        (__attribute__((address_space(3))) void*)l, 16, 0, 0);
}

__device__ inline unsigned short f2bf(float v) {
    uint32_t u = __builtin_bit_cast(uint32_t, v);
    return (unsigned short)((u + 0x7fffu + ((u >> 16) & 1u)) >> 16);   // RTNE
}

// reference-exact sq = ((x*x + y*y) + z*z), no FMA contraction
__device__ inline float sq_exact(float x, float y, float z) {
    return __fadd_rn(__fadd_rn(__fmul_rn(x, x), __fmul_rn(y, y)), __fmul_rn(z, z));
}

__device__ inline int cell_of(float x, float y, float z) {
    int cx = (int)(x * 8.0f); cx = min(max(cx, 0), 7);
    int cy = (int)(y * 8.0f); cy = min(max(cy, 0), 7);
    int cz = (int)(z * 8.0f); cz = min(max(cz, 0), 7);
    return (cx << 6) | (cy << 3) | cz;
}

__device__ inline int wmin(int v) {
    for (int off = 32; off >= 1; off >>= 1) v = min(v, __shfl_xor(v, off, 64));
    return v;
}

// ---------------- kernel 1: fused prep (unchanged from round 8) ----------------
__global__ __launch_bounds__(256) void fused_prep(const float* __restrict__ w,
                                                  unsigned short* __restrict__ wt,
                                                  const float* __restrict__ x,
                                                  unsigned short* __restrict__ xbf,
                                                  const float* __restrict__ pcs,
                                                  float4* __restrict__ sp4,
                                                  int* __restrict__ cellstart) {
    const int bid = blockIdx.x;
    const int tid = threadIdx.x;

    if (bid < 1024) {
        // ---- weight transpose ----
        int gidx = bid * 256 + tid;                   // 0..262143
        int o = gidx >> 10, k = gidx & 1023;
        int slot = k >> 7, cch = k & 127;             // slot 0=center, slot s=octant s-1
        wt[gidx] = f2bf(w[(size_t)o * 1152 + cch * 9 + slot]);
    } else if (bid < 1284) {
        // ---- feature transpose ----
        __shared__ __attribute__((aligned(16))) unsigned short tile[64 * 132];
        const int bb = bid - 1024;
        const int b = bb / 65;
        const int j0 = (bb % 65) * 64;
        if (j0 < N_PTS) {
            for (int c0 = 0; c0 < C_IN; c0 += 4) {
                int cc = c0 + (tid >> 6);
                int jj = tid & 63;
                float v = x[((size_t)b * C_IN + cc) * N_PTS + j0 + jj];
                tile[jj * 132 + cc] = f2bf(v);
            }
            __syncthreads();
            for (int i = 0; i < 8; ++i) {
                int idx = i * 256 + tid;      // 0..2047 -> 64 rows x 32 quads
                int row = idx >> 5, cq = idx & 31;
                uint2 v = *(const uint2*)&tile[row * 132 + cq * 4];
                *(uint2*)&xbf[((size_t)b * (N_PTS + 1) + j0 + row) * C_IN + cq * 4] = v;
            }
        } else {
            // zeros row j = 4096 (empty-octant gather target)
            for (int i = tid; i < C_IN; i += 256)
                xbf[((size_t)b * (N_PTS + 1) + N_PTS) * C_IN + i] = 0;
        }
    } else {
        // ---- grid build for batch b: count -> prefix -> scatter (LDS) ----
        __shared__ int scnt[NCELL];                   // counts -> cursors
        __shared__ int pairs[256];
        const int b = bid - 1284;
        const float* pb = pcs + (size_t)b * 3 * N_PTS;
        for (int i = tid; i < NCELL; i += 256) scnt[i] = 0;
        __syncthreads();
        // count (16 points per thread)
        for (int k = 0; k < 16; ++k) {
            int n = k * 256 + tid;
            atomicAdd(&scnt[cell_of(pb[n], pb[N_PTS + n], pb[2 * N_PTS + n])], 1);
        }
        __syncthreads();
        // exclusive prefix over 512 cells (2 cells/thread + Hillis-Steele on pair sums)
        const int a0 = scnt[2 * tid], a1 = scnt[2 * tid + 1];
        pairs[tid] = a0 + a1;
        __syncthreads();
        for (int off = 1; off < 256; off <<= 1) {
            int v = (tid >= off) ? pairs[tid - off] : 0;
            __syncthreads();
            pairs[tid] += v;
            __syncthreads();
        }
        const int epair = pairs[tid] - (a0 + a1);     // exclusive pair prefix
        cellstart[b * 513 + 2 * tid]     = epair;
        cellstart[b * 513 + 2 * tid + 1] = epair + a0;
        scnt[2 * tid]     = epair;                    // cursors
        scnt[2 * tid + 1] = epair + a0;
        if (tid == 255) cellstart[b * 513 + 512] = epair + a0 + a1;
        __syncthreads();
        // scatter: sp4[slot] = (x, y, z, bitcast(original index n))
        for (int k = 0; k < 16; ++k) {
            int n = k * 256 + tid;
            float px = pb[n], py = pb[N_PTS + n], pz = pb[2 * N_PTS + n];
            int slot = atomicAdd(&scnt[cell_of(px, py, pz)], 1);
            sp4[(b << 12) + slot] = make_float4(px, py, pz, __builtin_bit_cast(float, n));
        }
    }
}

// ---------------- kernel 2: grid ball query — cell-sorted center assignment -------
// Wave handles SORTED slot s (center coords read from sp4[s] itself — bit-identical
// floats); adjacent waves share the same 27-cell neighborhood (~3.5 KB) -> L1-resident
// candidate loads. XCD-chunked block swizzle keeps each XCD on one contiguous slot
// range. Output scattered to idxu[n] (per-center result is scatter-order-invariant
// -> deterministic). Octant firsts = order-free mins; 31-cap via rank check.
__global__ __launch_bounds__(256) void bq_grid(const float4* __restrict__ sp4,
                                               const int* __restrict__ cellstart,
                                               unsigned short* __restrict__ idxu) {
    __shared__ int lists[4 * 128];
    const int tid = threadIdx.x;
    const int wid = tid >> 6, lane = tid & 63;
    // XCD-chunked bijective swizzle (4096 blocks, 8 XCDs): consecutive logical
    // blocks stay on one XCD -> L2/L1 locality on the sorted stream.
    const int lb = ((blockIdx.x & 7) << 9) | (blockIdx.x >> 3);
    const int gw = (lb << 2) | wid;                   // global wave id 0..16383
    const int b = gw >> 12;
    const int sidx = gw & 4095;                       // cell-sorted slot
    const float4* sp = sp4 + ((size_t)b << 12);
    const int* cs = cellstart + b * 513;
    const float4 cp = sp[sidx];
    const float cxf = cp.x, cyf = cp.y, czf = cp.z;
    const int n = __builtin_bit_cast(int, cp.w);      // original center index
    const float csq = sq_exact(cxf, cyf, czf);        // bit-identical to reference
    const float r2 = (float)(0.12 * 0.12);

    int cx = min(max((int)(cxf * 8.0f), 0), 7);
    int cy = min(max((int)(cyf * 8.0f), 0), 7);
    int cz = min(max((int)(czf * 8.0f), 0), 7);
    const int zlo = max(cz - 1, 0), zhi = min(cz + 1, 7);

    // 9-run table (wave-uniform scalars, static names only — rule #20)
#define RUN(k, dx, dy)                                                              \
    int rs##k = 0, ln##k = 0;                                                       \
    {                                                                               \
        int gx = cx + (dx), gy = cy + (dy);                                         \
        if (gx >= 0 && gx <= 7 && gy >= 0 && gy <= 7) {                             \
            int cb_ = (gx << 6) | (gy << 3);                                        \
            rs##k = cs[cb_ + zlo];                                                  \
            ln##k = cs[cb_ + zhi + 1] - rs##k;                                      \
        }                                                                           \
    }
    RUN(0, -1, -1) RUN(1, -1, 0) RUN(2, -1, 1)
    RUN(3,  0, -1) RUN(4,  0, 0) RUN(5,  0, 1)
    RUN(6,  1, -1) RUN(7,  1, 0) RUN(8,  1, 1)
#undef RUN
    const int c1 = ln0;
    const int c2 = c1 + ln1;
    const int c3 = c2 + ln2;
    const int c4 = c3 + ln3;
    const int c5 = c4 + ln4;
    const int c6 = c5 + ln5;
    const int c7 = c6 + ln6;
    const int c8 = c7 + ln7;
    const int TT = c8 + ln8;                          // total candidates (~216 avg)

    // stream position -> cell-sorted slot (static cndmask chain, clamped safe)
#define CAND_IDX(T, OUTI)                                                           \
    {                                                                               \
        const int t_ = (T);                                                         \
        int i_ = rs0 + t_;                                                          \
        i_ = (t_ >= c1) ? (rs1 + t_ - c1) : i_;                                     \
        i_ = (t_ >= c2) ? (rs2 + t_ - c2) : i_;                                     \
        i_ = (t_ >= c3) ? (rs3 + t_ - c3) : i_;                                     \
        i_ = (t_ >= c4) ? (rs4 + t_ - c4) : i_;                                     \
        i_ = (t_ >= c5) ? (rs5 + t_ - c5) : i_;                                     \
        i_ = (t_ >= c6) ? (rs6 + t_ - c6) : i_;                                     \
        i_ = (t_ >= c7) ? (rs7 + t_ - c7) : i_;                                     \
        i_ = (t_ >= c8) ? (rs8 + t_ - c8) : i_;                                     \
        OUTI = (t_ < TT) ? i_ : rs4;   /* rs4 = center's own cell, always valid */  \
    }

    int f0 = BIGJ, f1 = BIGJ, f2 = BIGJ, f3 = BIGJ, f4 = BIGJ, f5 = BIGJ, f6 = BIGJ;
    int cnt = 0;
    int* lst = &lists[wid * 128];
    const unsigned long long ltm = (1ull << lane) - 1ull;

    int ic0;
    CAND_IDX(lane, ic0)
    float4 p_cur = sp[ic0];                           // prologue load (TT >= 1 always)

    for (int t0 = 0; t0 < TT; t0 += 64) {
        int icn;
        CAND_IDX(t0 + 64 + lane, icn)
        const float4 p_nxt = sp[icn];                 // prefetch next chunk

        const bool valid = (t0 + lane) < TT;
        const float4 p = p_cur;
        const int j = __builtin_bit_cast(int, p.w);
        const float psq = sq_exact(p.x, p.y, p.z);    // bit-identical to reference
        float dot = __fadd_rn(__fadd_rn(__fmul_rn(cxf, p.x), __fmul_rn(cyf, p.y)),
                              __fmul_rn(czf, p.z));
        float dd = __fsub_rn(__fadd_rn(csq, psq), __fmul_rn(2.0f, dot));
        const bool ok = valid && (dd <= r2) && (j != n);
        unsigned long long m = __ballot(ok);
        if (m) {
            int pos = cnt + __popcll(m & ltm);
            if (ok && pos < 128) lst[pos] = j;
            cnt += __popcll(m);
            const int oct = ((p.x >= cxf) ? 4 : 0) + ((p.y >= cyf) ? 2 : 0)
                          + ((p.z >= czf) ? 1 : 0);
            const int key = ok ? j : BIGJ;
            f0 = (oct == 0) ? min(f0, key) : f0;
            f1 = (oct == 1) ? min(f1, key) : f1;
            f2 = (oct == 2) ? min(f2, key) : f2;
            f3 = (oct == 3) ? min(f3, key) : f3;
            f4 = (oct == 4) ? min(f4, key) : f4;
            f5 = (oct == 5) ? min(f5, key) : f5;
            f6 = (oct == 6) ? min(f6, key) : f6;
        }
        p_cur = p_nxt;
    }
#undef CAND_IDX

    f0 = wmin(f0); f1 = wmin(f1); f2 = wmin(f2); f3 = wmin(f3);
    f4 = wmin(f4); f5 = wmin(f5); f6 = wmin(f6);

    if (cnt > 31) {
        // rank check against the (<=128) recorded matches; cnt>128 has ~0
        // probability at lambda~30 (same exposure as the sort it replaced)
        const int c2_ = min(cnt, 128);
        const int l0 = (lane < c2_) ? lst[lane] : BIGJ;
        const int l1 = (64 + lane < c2_) ? lst[64 + lane] : BIGJ;
#define RANKCHK(F)                                                                  \
        {                                                                           \
            int r_ = __popcll(__ballot(l0 < F)) + __popcll(__ballot(l1 < F));       \
            F = (r_ <= 30) ? F : BIGJ;                                              \
        }
        RANKCHK(f0) RANKCHK(f1) RANKCHK(f2) RANKCHK(f3)
        RANKCHK(f4) RANKCHK(f5) RANKCHK(f6)
#undef RANKCHK
    }

    int v = n;                                        // lane 0: center index
    if (lane == 1) v = f0;
    if (lane == 2) v = f1;
    if (lane == 3) v = f2;
    if (lane == 4) v = f3;
    if (lane == 5) v = f4;
    if (lane == 6) v = f5;
    if (lane == 7) v = f6;
    if (v > N_PTS) v = N_PTS;                         // BIGJ -> zeros row
    if (lane < 8) idxu[((size_t)((b << 12) | n)) * 8 + lane] = (unsigned short)v;
}

// ---------------- kernel 3: gathered GEMM, 128x128 tile, 2-phase double-buffer ------
// 8 waves (512 thr), BK=64, 1 block/CU. T3-minimum: STAGE(next) issued before
// COMPUTE(cur), one __syncthreads (vmcnt0+barrier) per iter -> stage latency hides
// under MFMA. Gather indices hoisted to jlds once (kills per-iter idxu->gload chain).
__global__ __launch_bounds__(512) void pconv_gemm(const unsigned short* __restrict__ xbf,
                                                  const unsigned short* __restrict__ wt,
                                                  const unsigned short* __restrict__ idxu,
                                                  const float* __restrict__ bias,
                                                  float* __restrict__ out) {
    __shared__ __attribute__((aligned(16))) unsigned short Plds[2][128 * 64];
    __shared__ __attribute__((aligned(16))) unsigned short Wlds[2][128 * 64];
    __shared__ unsigned short jlds[128 * 8];
    const int tid = threadIdx.x;
    const int tm = blockIdx.x >> 1, tn = blockIdx.x & 1;  // 128 M-tiles x 2 N-tiles
    const int g0 = tm * 128;                 // global point-row base
    const int b  = g0 >> 12;
    const int nb = g0 & 4095;
    const int o0 = tn * 128;
    const int wid = tid >> 6, lane = tid & 63;
    const int wo = wid >> 1, wn = wid & 1;   // wave -> 32 o-rows x 64 n-cols

    // hoist all gather indices for this block (1024 u16, coalesced)
    for (int i = tid; i < 1024; i += 512) jlds[i] = idxu[(size_t)g0 * 8 + i];
    __syncthreads();

    f32x4 acc[2][4] = {};

#define STAGE(BUF, IT)                                                              \
    {                                                                               \
        const int k0_ = (IT) << 6;                                                  \
        const int slot_ = (IT) >> 1;                                                \
        const int cb_ = ((IT) & 1) << 6;                                            \
        _Pragma("unroll")                                                           \
        for (int i_ = 0; i_ < 2; ++i_) {                                            \
            const int Lb_ = i_ * 512 + wid * 64;                                    \
            const int row_ = (Lb_ + lane) >> 3;                                     \
            const int slog_ = (lane & 7) ^ (row_ & 7);                              \
            int j_ = jlds[row_ * 8 + slot_];                                        \
            gload_lds16(xbf + ((size_t)b * (N_PTS + 1) + j_) * C_IN + cb_ + slog_ * 8, \
                        &Plds[BUF][Lb_ * 8]);                                       \
            gload_lds16(wt + (size_t)(o0 + row_) * KDIM + k0_ + slog_ * 8,          \
                        &Wlds[BUF][Lb_ * 8]);                                       \
        }                                                                           \
    }

    STAGE(0, 0)
    __syncthreads();                          // vmcnt(0) drain: buf0 ready

    for (int it = 0; it < 16; ++it) {
        const int cur = it & 1;
        if (it + 1 < 16) STAGE(cur ^ 1, it + 1)   // prefetch next K-step
#pragma unroll
        for (int ks = 0; ks < 2; ++ks) {
            bf16x8 wf[2], pf[4];
#pragma unroll
            for (int f = 0; f < 2; ++f) {
                int orow = wo * 32 + f * 16 + (lane & 15);
                int slw = (ks * 4 + (lane >> 4)) ^ (orow & 7);
                wf[f] = *(const bf16x8*)&Wlds[cur][orow * 64 + slw * 8];
            }
#pragma unroll
            for (int q = 0; q < 4; ++q) {
                int nrow = wn * 64 + q * 16 + (lane & 15);
                int slp = (ks * 4 + (lane >> 4)) ^ (nrow & 7);
                pf[q] = *(const bf16x8*)&Plds[cur][nrow * 64 + slp * 8];
            }
#pragma unroll
            for (int f = 0; f < 2; ++f)
#pragma unroll
                for (int q = 0; q < 4; ++q)
                    acc[f][q] = __builtin_amdgcn_mfma_f32_16x16x32_bf16(
                        wf[f], pf[q], acc[f][q], 0, 0, 0);
        }
        __syncthreads();                      // next buf staged + this buf's reads done
    }
#undef STAGE

#pragma unroll
    for (int f = 0; f < 2; ++f) {
        int o = o0 + wo * 32 + f * 16 + (lane >> 4) * 4;
#pragma unroll
        for (int q = 0; q < 4; ++q) {
            int n = nb + wn * 64 + q * 16 + (lane & 15);
#pragma unroll
            for (int r = 0; r < 4; ++r) {
                out[((size_t)b * C_OUT + o + r) * N_PTS + n] = acc[f][q][r] + bias[o + r];
            }
        }
    }
}

extern "C" void kernel_launch(void* const* d_in, const int* in_sizes, int n_in,
                              void* d_out, int out_size, void* d_ws, size_t ws_size,
                              hipStream_t stream) {
    const float* x    = (const float*)d_in[0];
    const float* pcs  = (const float*)d_in[1];
    const float* w    = (const float*)d_in[2];
    const float* bias = (const float*)d_in[3];

    // ws layout (bytes) — total 5,252,112 < 5,506,048 proven-safe (rounds 1-3):
    char* base = (char*)d_ws;
    float4* sp4 = (float4*)base;                                    //       0 (262,144)
    unsigned short* xbf = (unsigned short*)(base + 262144);         // 4,195,328
    unsigned short* wt  = (unsigned short*)(base + 4457472);        //   524,288
    unsigned short* idxu = (unsigned short*)(base + 4981760);       //   262,144
    int* cellstart = (int*)(base + 5243904);                        //     8,208
    float* out = (float*)d_out;

    hipLaunchKernelGGL(fused_prep, dim3(1288), dim3(256), 0, stream,
                       w, wt, x, xbf, pcs, sp4, cellstart);
    hipLaunchKernelGGL(bq_grid,    dim3(4096), dim3(256), 0, stream,
                       sp4, cellstart, idxu);
    hipLaunchKernelGGL(pconv_gemm, dim3(256),  dim3(512), 0, stream,
                       xbf, wt, idxu, bias, out);
}